// Round 8
// baseline (1186.587 us; speedup 1.0000x reference)
//
#include <hip/hip_runtime.h>
#include <cstdint>
#include <cstddef>

typedef __attribute__((ext_vector_type(8))) short short8;
typedef __attribute__((ext_vector_type(8))) _Float16 half8;
typedef __attribute__((ext_vector_type(4))) float floatx4;
typedef __attribute__((ext_vector_type(4))) int intx4;
typedef __attribute__((ext_vector_type(4))) unsigned short ushort4v;

__device__ __forceinline__ unsigned short f2h(float f) {
    union { _Float16 h; unsigned short u; } v;
    v.h = (_Float16)f;
    return v.u;
}
__device__ __forceinline__ float h2f(unsigned short u) {
    union { unsigned short u; _Float16 h; } v;
    v.u = u;
    return (float)v.h;
}
// relu that propagates NaN (fmaxf would silently map NaN->0 and hide bugs)
__device__ __forceinline__ float relu_keepnan(float v) {
    return v > 0.f ? v : (v == v ? 0.f : v);
}

// ---------------- f32 -> f16 weight convert ----------------------------------------
__global__ __launch_bounds__(256) void k_cvt(
    const float* __restrict__ src, unsigned short* __restrict__ dst, int n) {
    int i = blockIdx.x * 256 + threadIdx.x;
    if (i < n) dst[i] = f2h(src[i]);
}

// ------- precompute, laid out [layer][n][ch]:
// lwc = (wre, wim, Re(c2), Im(c2)),  wt = w^128 (segment propagator)
__global__ __launch_bounds__(256) void k_precompute(
    const float* __restrict__ ldt, const float* __restrict__ lar,
    const float* __restrict__ aim, const float* __restrict__ cre,
    const float* __restrict__ cim, float4* __restrict__ lwc,
    float2* __restrict__ wt) {
    int idx = blockIdx.x * 256 + threadIdx.x;      // [4][512][32]
    int i = idx >> 14;
    int h = (idx >> 5) & 511;
    int n = idx & 31;
    float dt = expf(ldt[i * 512 + h]);
    float Are = -expf(lar[idx]);
    float Aim = aim[idx];
    float dre = dt * Are, dim = dt * Aim;
    float e = expf(dre);
    float wre = e * cosf(dim);
    float wim = e * sinf(dim);
    float emr = wre - 1.f, emi = wim;              // expm1(dtA)
    float inv = 1.f / (Are * Are + Aim * Aim);
    float fr = (emr * Are + emi * Aim) * inv;      // expm1(dtA)/A
    float fi = (emi * Are - emr * Aim) * inv;
    float cr = cre[idx], ci = cim[idx];
    float4 o;
    o.x = wre; o.y = wim;
    o.z = 2.f * (cr * fr - ci * fi);               // Re(c2)
    o.w = 2.f * (cr * fi + ci * fr);               // Im(c2)
    int oidx = (i * 32 + n) * 512 + h;             // [layer][n][ch]
    lwc[oidx] = o;
    float ar = wre, ai = wim;                      // w^128 by 7 squarings
#pragma unroll
    for (int k = 0; k < 7; ++k) {
        float nr = ar * ar - ai * ai;
        float ni = 2.f * ar * ai;
        ar = nr; ai = ni;
    }
    wt[oidx] = make_float2(ar, ai);
}

// ---------------- quantize (round-half-even) + transpose (B,C,L)f32 -> (J,C) f16 ----
__global__ __launch_bounds__(256) void k_quant_transpose(
    const float* __restrict__ x, unsigned short* __restrict__ xq, int b0) {
    __shared__ unsigned short tile[64][65];
    const int bg = b0 + blockIdx.z, bl = blockIdx.z;
    const int c0 = blockIdx.y * 64, t0 = blockIdx.x * 64;
    const int tid = threadIdx.x;
#pragma unroll
    for (int it = 0; it < 16; ++it) {
        int idx = it * 256 + tid;
        int r = idx >> 6, cc = idx & 63;
        float f = x[(size_t)(bg * 512 + c0 + r) * 2048 + t0 + cc];
        float q = rintf(f * 64.f) * 0.015625f;     // k/64: exact in f16
        tile[r][cc] = f2h(q);
    }
    __syncthreads();
#pragma unroll
    for (int it = 0; it < 16; ++it) {
        int idx = it * 256 + tid;
        int r = idx >> 6, cc = idx & 63;           // r = t-local, cc = c-local
        xq[(size_t)(bl * 2048 + t0 + r) * 512 + c0 + cc] = tile[cc][r];
    }
}

// ---------------- build WA[h][n2][k] = Re/Im(w^(127-k)) f16 (per layer) -------------
__global__ __launch_bounds__(64) void k_build_wa(
    const float4* __restrict__ lwc, unsigned short* __restrict__ WA, int layer) {
    __shared__ unsigned short Ws[64 * 136];
    const int h = blockIdx.x, tid = threadIdx.x;
    if (tid < 32) {
        float4 v = lwc[((size_t)layer * 32 + tid) * 512 + h];
        float pr = 1.f, pi = 0.f;                  // w^0
        for (int m = 0; m < 128; ++m) {
            Ws[(2 * tid) * 136 + (127 - m)] = f2h(pr);
            Ws[(2 * tid + 1) * 136 + (127 - m)] = f2h(pi);
            float nr = pr * v.x - pi * v.y;
            float ni = pr * v.y + pi * v.x;
            pr = nr; pi = ni;
        }
    }
    __syncthreads();
#pragma unroll
    for (int it = 0; it < 16; ++it) {
        int idx = it * 64 + tid;                   // 1024 chunks of 8
        int r = idx >> 4, c8 = idx & 15;
        *(intx4*)(WA + (size_t)h * 8192 + r * 128 + c8 * 8) =
            *(const intx4*)(Ws + r * 136 + c8 * 8);
    }
}

// ------- build TT[h][t][192] f16 (per layer): [Toeplitz K(t-k)+D | cross c2*w^(t+1)]
__global__ __launch_bounds__(256) void k_build_T(
    const float4* __restrict__ lwc, const float* __restrict__ Dp,
    unsigned short* __restrict__ TT, int layer) {
    __shared__ float Kvs[128];
    __shared__ unsigned short Mxs[128 * 64];
    __shared__ float wr_s[32], wi_s[32], cr_s[32], ci_s[32];
    const int h = blockIdx.x, tid = threadIdx.x;
    if (tid < 32) {
        float4 v = lwc[((size_t)layer * 32 + tid) * 512 + h];
        wr_s[tid] = v.x; wi_s[tid] = v.y; cr_s[tid] = v.z; ci_s[tid] = v.w;
    }
    __syncthreads();
    if (tid < 32) {
        const int n = tid;
        float wre = wr_s[n], wim = wi_s[n];
        float ar = cr_s[n], ai = ci_s[n];          // c2 * w^0
        for (int m = 0; m <= 128; ++m) {
            if (m < 128) {                          // K[m] = sum_n Re(c2 w^m)
                float s = ar;
#pragma unroll
                for (int d = 16; d >= 1; d >>= 1) s += __shfl_xor(s, d, 64);
                if (n == 0) Kvs[m] = s;
            }
            if (m >= 1) {                           // cross row t = m-1 uses w^m
                Mxs[(m - 1) * 64 + 2 * n] = f2h(ar);
                Mxs[(m - 1) * 64 + 2 * n + 1] = f2h(-ai);
            }
            float nr = ar * wre - ai * wim;
            float ni = ar * wim + ai * wre;
            ar = nr; ai = ni;
        }
    }
    __syncthreads();
    const float Dh = Dp[layer * 512 + h];
#pragma unroll
    for (int it = 0; it < 12; ++it) {
        int idx = it * 256 + tid;                  // 3072 chunks of 8
        int t = idx / 24, c8 = idx % 24;
        short8 pack;
#pragma unroll
        for (int q = 0; q < 8; ++q) {
            int k = c8 * 8 + q;
            unsigned short us;
            if (k < 128) {
                float val = (k <= t) ? (Kvs[t - k] + (k == t ? Dh : 0.f)) : 0.f;
                us = f2h(val);
            } else {
                us = Mxs[t * 64 + (k - 128)];
            }
            pack[q] = (short)us;
        }
        *(short8*)(TT + (size_t)h * 24576 + t * 192 + c8 * 8) = pack;
    }
}

// ---------------- f16 MFMA GEMM: C[m,j] = sum_k A[m,k]*Bm[j,k], K=512 ---------------
// grid (j-tiles, m-tiles): same-j blocks are gridDim.x apart (mult of 8) -> same XCD.
// MODE 0: relu -> hf f16 (j,512) AND ut f16 (512,J)   MODE 2: relu -> d_out (B,512,L)
template <int MODE>
__global__ __launch_bounds__(256, 2) void k_gemm(
    const unsigned short* __restrict__ A, const unsigned short* __restrict__ Bm,
    float* __restrict__ of32, unsigned short* __restrict__ o16,
    unsigned short* __restrict__ ut, int J, int b0) {
    __shared__ __align__(16) unsigned short lds[2 * 128 * 72];
    unsigned short* Al = lds;
    unsigned short* Bl = lds + 128 * 72;
    const int tid = threadIdx.x;
    const int m0 = blockIdx.y * 128;
    const int j0 = blockIdx.x * 128;
    const int sub = tid & 7;
    const int row = tid >> 3;
    const unsigned short* Ag = A + (size_t)(m0 + row) * 512 + sub * 8;
    const unsigned short* Bg = Bm + (size_t)(j0 + row) * 512 + sub * 8;
    intx4 ra[4], rb[4];
#pragma unroll
    for (int i = 0; i < 4; ++i) {
        ra[i] = *(const intx4*)(Ag + (size_t)i * 32 * 512);
        rb[i] = *(const intx4*)(Bg + (size_t)i * 32 * 512);
    }
    const int lane = tid & 63;
    const int w = tid >> 6;
    const int wm = w & 1, wn = w >> 1;
    const int l15 = lane & 15, quad = lane >> 4;
    floatx4 acc[4][4] = {};
    for (int kt = 0; kt < 8; ++kt) {
#pragma unroll
        for (int i = 0; i < 4; ++i) {
            *(intx4*)(Al + (row + 32 * i) * 72 + sub * 8) = ra[i];
            *(intx4*)(Bl + (row + 32 * i) * 72 + sub * 8) = rb[i];
        }
        __syncthreads();
        if (kt < 7) {
#pragma unroll
            for (int i = 0; i < 4; ++i) {
                ra[i] = *(const intx4*)(Ag + (size_t)i * 32 * 512 + (kt + 1) * 64);
                rb[i] = *(const intx4*)(Bg + (size_t)i * 32 * 512 + (kt + 1) * 64);
            }
        }
#pragma unroll
        for (int ks = 0; ks < 2; ++ks) {
            half8 af[4], bfr[4];
#pragma unroll
            for (int mt = 0; mt < 4; ++mt)
                af[mt] = *(const half8*)(Al + (wm * 64 + mt * 16 + l15) * 72 + ks * 32 + quad * 8);
#pragma unroll
            for (int nt = 0; nt < 4; ++nt)
                bfr[nt] = *(const half8*)(Bl + (wn * 64 + nt * 16 + l15) * 72 + ks * 32 + quad * 8);
#pragma unroll
            for (int mt = 0; mt < 4; ++mt)
#pragma unroll
                for (int nt = 0; nt < 4; ++nt)
                    acc[mt][nt] = __builtin_amdgcn_mfma_f32_16x16x32_f16(
                        af[mt], bfr[nt], acc[mt][nt], 0, 0, 0);
        }
        __syncthreads();
    }
#pragma unroll
    for (int mt = 0; mt < 4; ++mt) {
#pragma unroll
        for (int nt = 0; nt < 4; ++nt) {
            const int dl = wm * 64 + mt * 16 + quad * 4;       // C/D row = quad*4+reg
            const int jl = wn * 64 + nt * 16 + l15;            // C/D col = lane&15
            floatx4 v = acc[mt][nt];
#pragma unroll
            for (int r = 0; r < 4; ++r) v[r] = relu_keepnan(v[r]);
            if (MODE == 0) {
                ushort4v hv;
#pragma unroll
                for (int r = 0; r < 4; ++r) hv[r] = f2h(v[r]);
                *(ushort4v*)(o16 + (size_t)(j0 + jl) * 512 + m0 + dl) = hv;
                // stage f16 into lds tile [d][j] (stride 136) for the ut transpose
#pragma unroll
                for (int r = 0; r < 4; ++r) lds[(dl + r) * 136 + jl] = hv[r];
            } else {
                const int j = j0 + jl;
                const int bl = j >> 11, t = j & 2047;
#pragma unroll
                for (int r = 0; r < 4; ++r)
                    of32[((size_t)((b0 + bl) * 512 + m0 + dl + r)) * 2048 + t] = v[r];
            }
        }
    }
    if (MODE == 0) {
        __syncthreads();
        const int drow = tid >> 1, hh = tid & 1;
        const unsigned short* srcp = lds + drow * 136 + hh * 64;
        unsigned short* dstp = ut + (size_t)(m0 + drow) * J + j0 + hh * 64;
#pragma unroll
        for (int q = 0; q < 8; ++q)
            *(intx4*)(dstp + q * 8) = *(const intx4*)(srcp + q * 8);
    }
}

// ---------------- phase A GEMM: P[h][n2][r] = sum_k WA[h][n2][k] * ut[h][r][k] -------
__global__ __launch_bounds__(256, 4) void k_stateA(
    const unsigned short* __restrict__ WA, const unsigned short* __restrict__ ut,
    float* __restrict__ P, int J, int Rtot) {
    __shared__ __align__(16) unsigned short Aw[64 * 72];
    __shared__ __align__(16) unsigned short Bw[128 * 72];
    const int tid = threadIdx.x;
    const int h = blockIdx.y;
    const int r0 = blockIdx.x * 128;
    const int sub = tid & 7, row = tid >> 3;
    const unsigned short* Ag = WA + (size_t)h * 8192 + row * 128 + sub * 8;
    const unsigned short* Bg = ut + (size_t)h * J + (size_t)(r0 + row) * 128 + sub * 8;
    intx4 ra[2], rb[4];
    ra[0] = *(const intx4*)(Ag);
    ra[1] = *(const intx4*)(Ag + 32 * 128);
#pragma unroll
    for (int i = 0; i < 4; ++i) rb[i] = *(const intx4*)(Bg + i * 32 * 128);
    const int lane = tid & 63, w = tid >> 6;
    const int wm = w & 1, wn = w >> 1;
    const int l15 = lane & 15, quad = lane >> 4;
    floatx4 acc[2][4] = {};
    for (int kt = 0; kt < 2; ++kt) {
        *(intx4*)(Aw + row * 72 + sub * 8) = ra[0];
        *(intx4*)(Aw + (row + 32) * 72 + sub * 8) = ra[1];
#pragma unroll
        for (int i = 0; i < 4; ++i)
            *(intx4*)(Bw + (row + 32 * i) * 72 + sub * 8) = rb[i];
        __syncthreads();
        if (kt == 0) {
            ra[0] = *(const intx4*)(Ag + 64);
            ra[1] = *(const intx4*)(Ag + 32 * 128 + 64);
#pragma unroll
            for (int i = 0; i < 4; ++i) rb[i] = *(const intx4*)(Bg + i * 32 * 128 + 64);
        }
#pragma unroll
        for (int ks = 0; ks < 2; ++ks) {
            half8 af[2], bfr[4];
#pragma unroll
            for (int mt = 0; mt < 2; ++mt)
                af[mt] = *(const half8*)(Aw + (wm * 32 + mt * 16 + l15) * 72 + ks * 32 + quad * 8);
#pragma unroll
            for (int nt = 0; nt < 4; ++nt)
                bfr[nt] = *(const half8*)(Bw + (wn * 64 + nt * 16 + l15) * 72 + ks * 32 + quad * 8);
#pragma unroll
            for (int mt = 0; mt < 2; ++mt)
#pragma unroll
                for (int nt = 0; nt < 4; ++nt)
                    acc[mt][nt] = __builtin_amdgcn_mfma_f32_16x16x32_f16(
                        af[mt], bfr[nt], acc[mt][nt], 0, 0, 0);
        }
        __syncthreads();
    }
#pragma unroll
    for (int mt = 0; mt < 2; ++mt)
#pragma unroll
        for (int nt = 0; nt < 4; ++nt)
#pragma unroll
            for (int r = 0; r < 4; ++r)
                P[((size_t)h * 64 + wm * 32 + mt * 16 + quad * 4 + r) * Rtot +
                  r0 + wn * 64 + nt * 16 + l15] = acc[mt][nt][r];
}

// ---------------- combine: S0[h][r][n2] f16, exclusive prefix over 16 segments -------
__global__ __launch_bounds__(64) void k_comb(
    const float* __restrict__ P, const float2* __restrict__ wt,
    unsigned short* __restrict__ S0, int layer, int Rtot) {
    __shared__ float Ps[64][17];
    __shared__ unsigned short S0s[16][64];
    const int h = blockIdx.x, bl = blockIdx.y;
    const int tid = threadIdx.x;
#pragma unroll
    for (int it = 0; it < 4; ++it) {
        int idx = it * 64 + tid;                   // 256 float4
        int n2 = idx >> 2, pt = idx & 3;
        float4 v = *(const float4*)(P + ((size_t)h * 64 + n2) * Rtot + bl * 16 + pt * 4);
        Ps[n2][pt * 4 + 0] = v.x; Ps[n2][pt * 4 + 1] = v.y;
        Ps[n2][pt * 4 + 2] = v.z; Ps[n2][pt * 4 + 3] = v.w;
    }
    __syncthreads();
    if (tid < 32) {
        const int n = tid;
        float2 wv = wt[((size_t)layer * 32 + n) * 512 + h];
        float ar = 0.f, ai = 0.f;
        for (int g = 0; g < 16; ++g) {
            S0s[g][2 * n] = f2h(ar);
            S0s[g][2 * n + 1] = f2h(ai);
            float pr = Ps[2 * n][g], pi = Ps[2 * n + 1][g];
            float nr = fmaf(wv.x, ar, fmaf(-wv.y, ai, pr));
            float ni = fmaf(wv.x, ai, fmaf(wv.y, ar, pi));
            ar = nr; ai = ni;
        }
    }
    __syncthreads();
    const int g = tid >> 2, pt = tid & 3;
    unsigned short* dst = S0 + ((size_t)h * Rtot + bl * 16 + g) * 64 + pt * 16;
    *(intx4*)(dst) = *(const intx4*)(&S0s[g][pt * 16]);
    *(intx4*)(dst + 8) = *(const intx4*)(&S0s[g][pt * 16 + 8]);
}

// ---------------- phase B GEMM + gelu: vt[h][r*128+t] = gelu(sum_k TT[t][k]*[ut|S0]) -
__global__ __launch_bounds__(256, 2) void k_applyB(
    const unsigned short* __restrict__ TT, const unsigned short* __restrict__ ut,
    const unsigned short* __restrict__ S0, unsigned short* __restrict__ vt,
    int J, int Rtot) {
    __shared__ __align__(16) unsigned short lds[2 * 128 * 72];
    unsigned short* Al = lds;
    unsigned short* Bl = lds + 128 * 72;
    const int tid = threadIdx.x;
    const int h = blockIdx.y;
    const int r0 = blockIdx.x * 128;
    const int sub = tid & 7, row = tid >> 3;
    const unsigned short* Ag = TT + (size_t)h * 24576 + row * 192 + sub * 8;
    const unsigned short* Bu = ut + (size_t)h * J + (size_t)(r0 + row) * 128 + sub * 8;
    const unsigned short* Bs = S0 + ((size_t)h * Rtot + r0 + row) * 64 + sub * 8;
    intx4 ra[4], rb[4];
#pragma unroll
    for (int i = 0; i < 4; ++i) {
        ra[i] = *(const intx4*)(Ag + i * 32 * 192);
        rb[i] = *(const intx4*)(Bu + i * 32 * 128);
    }
    const int lane = tid & 63, w = tid >> 6;
    const int wm = w & 1, wn = w >> 1;
    const int l15 = lane & 15, quad = lane >> 4;
    floatx4 acc[4][4] = {};
    for (int kt = 0; kt < 3; ++kt) {
#pragma unroll
        for (int i = 0; i < 4; ++i) {
            *(intx4*)(Al + (row + 32 * i) * 72 + sub * 8) = ra[i];
            *(intx4*)(Bl + (row + 32 * i) * 72 + sub * 8) = rb[i];
        }
        __syncthreads();
        if (kt == 0) {
#pragma unroll
            for (int i = 0; i < 4; ++i) {
                ra[i] = *(const intx4*)(Ag + i * 32 * 192 + 64);
                rb[i] = *(const intx4*)(Bu + i * 32 * 128 + 64);
            }
        } else if (kt == 1) {
#pragma unroll
            for (int i = 0; i < 4; ++i) {
                ra[i] = *(const intx4*)(Ag + i * 32 * 192 + 128);
                rb[i] = *(const intx4*)(Bs + i * 32 * 64);
            }
        }
#pragma unroll
        for (int ks = 0; ks < 2; ++ks) {
            half8 af[4], bfr[4];
#pragma unroll
            for (int mt = 0; mt < 4; ++mt)
                af[mt] = *(const half8*)(Al + (wm * 64 + mt * 16 + l15) * 72 + ks * 32 + quad * 8);
#pragma unroll
            for (int nt = 0; nt < 4; ++nt)
                bfr[nt] = *(const half8*)(Bl + (wn * 64 + nt * 16 + l15) * 72 + ks * 32 + quad * 8);
#pragma unroll
            for (int mt = 0; mt < 4; ++mt)
#pragma unroll
                for (int nt = 0; nt < 4; ++nt)
                    acc[mt][nt] = __builtin_amdgcn_mfma_f32_16x16x32_f16(
                        af[mt], bfr[nt], acc[mt][nt], 0, 0, 0);
        }
        __syncthreads();
    }
    // epilogue: gelu -> f16, LDS tile [r][t] (stride 136), then coalesced copy-out
#pragma unroll
    for (int mt = 0; mt < 4; ++mt)
#pragma unroll
        for (int nt = 0; nt < 4; ++nt) {
            const int tl = wm * 64 + mt * 16 + quad * 4;   // D row = t
            const int rl = wn * 64 + nt * 16 + l15;        // D col = r
            ushort4v pack;
#pragma unroll
            for (int r = 0; r < 4; ++r) {
                float y = acc[mt][nt][r];
                float ge = 0.5f * y * (1.f + erff(y * 0.70710678118654752f));
                pack[r] = f2h(ge);
            }
            *(ushort4v*)(lds + rl * 136 + tl) = pack;
        }
    __syncthreads();
    const int rl2 = tid >> 1, hh = tid & 1;
    const unsigned short* srcp = lds + rl2 * 136 + hh * 64;
    unsigned short* dstp = vt + (size_t)h * J + (size_t)(r0 + rl2) * 128 + hh * 64;
#pragma unroll
    for (int q = 0; q < 8; ++q)
        *(intx4*)(dstp + q * 8) = *(const intx4*)(srcp + q * 8);
}

// ------- fused W_out GEMM + GLU: g_out[j,d] = (a+b1)*sigmoid(g+b2), f16 out ----------
// A-operand direct from global (W_out is L2-resident, fragment loads are 64B-dense).
// B double-buffered in LDS -> ONE barrier per K-step (prefetch issued after barrier so
// the pre-barrier vmcnt(0) drain never waits on it). Epilogue: GLU -> f16 via LDS
// transpose tile -> coalesced 16B stores (f16 8B scattered stores cost +20us, R5).
__global__ __launch_bounds__(256, 2) void k_gemm_glu(
    const unsigned short* __restrict__ A,   // W_out layer (1024,512) f16
    const unsigned short* __restrict__ Bt,  // vt (512, J) f16
    const float* __restrict__ bias,         // b_out layer (1024) f32
    unsigned short* __restrict__ g_out, int J) {  // (J,512) f16
    __shared__ __align__(16) unsigned short Bl[2 * 128 * 72];  // dbuf B; epilogue tile
    const int tid = threadIdx.x;
    const int m0 = blockIdx.y * 128;
    const int j0 = blockIdx.x * 128;
    // B staging map: channel pair (2*chp, 2*chp+1) chp 0..31, j-octets jo and jo+8
    const int chp = tid >> 3, jo = tid & 7;
    const unsigned short* Bg = Bt + (size_t)(2 * chp) * J + j0 + jo * 8;
    const int lane = tid & 63;
    const int w = tid >> 6;
    const int wm = w & 1, wn = w >> 1;               // 2x2 waves: m 2x64, n 2x64
    const int l15 = lane & 15, quad = lane >> 4;
    // per-thread A fragment base: row m0 + wm*64 + l15 (+mt*16), col quad*8 (+kt*64+ks*32)
    const unsigned short* A1f = A + (size_t)(m0 + wm * 64 + l15) * 512 + quad * 8;
    const unsigned short* A2f = A1f + 512 * 512;
    intx4 rb[4];
    rb[0] = *(const intx4*)(Bg);
    rb[1] = *(const intx4*)(Bg + J);
    rb[2] = *(const intx4*)(Bg + 64);
    rb[3] = *(const intx4*)(Bg + J + 64);
    // swizzled column base for B writes: colblk' = (chp>>2) ^ ((j>>3)&7)
    const int colbase = (((chp >> 2) ^ jo) << 3) + (chp & 3) * 2;
    floatx4 ac1[4][4] = {}, ac2[4][4] = {};
    for (int kt = 0; kt < 8; ++kt) {
        // write current rb into buffer kt&1 (other buffer may still be being read)
        {
            unsigned int* B32 = (unsigned int*)(Bl + (kt & 1) * 9216);
#pragma unroll
            for (int half = 0; half < 2; ++half) {
                const int jb = (jo + half * 8) * 8;
                intx4 e0 = rb[half * 2], e1 = rb[half * 2 + 1];
#pragma unroll
                for (int i = 0; i < 4; ++i) {
                    unsigned int ae = (unsigned int)e0[i], be = (unsigned int)e1[i];
                    unsigned int lo = (ae & 0xffffu) | (be << 16);        // j = jb+2i
                    unsigned int hi = (ae >> 16) | (be & 0xffff0000u);    // j = jb+2i+1
                    B32[((jb + 2 * i) * 72 + colbase) >> 1] = lo;
                    B32[((jb + 2 * i + 1) * 72 + colbase) >> 1] = hi;
                }
            }
        }
        __syncthreads();     // writes of buf kt&1 visible; also fences reuse (see proof)
        if (kt < 7) {        // prefetch AFTER barrier: overlaps the MFMA section below
            rb[0] = *(const intx4*)(Bg + (size_t)(kt + 1) * 64 * J);
            rb[1] = *(const intx4*)(Bg + (size_t)(kt + 1) * 64 * J + J);
            rb[2] = *(const intx4*)(Bg + (size_t)(kt + 1) * 64 * J + 64);
            rb[3] = *(const intx4*)(Bg + (size_t)(kt + 1) * 64 * J + J + 64);
        }
        const unsigned short* Bcur = Bl + (kt & 1) * 9216;
#pragma unroll
        for (int ks = 0; ks < 2; ++ks) {
            half8 af1[4], af2[4], bfr[4];
#pragma unroll
            for (int mt = 0; mt < 4; ++mt) {
                af1[mt] = *(const half8*)(A1f + (size_t)mt * 16 * 512 + kt * 64 + ks * 32);
                af2[mt] = *(const half8*)(A2f + (size_t)mt * 16 * 512 + kt * 64 + ks * 32);
            }
#pragma unroll
            for (int nt = 0; nt < 4; ++nt) {
                const int rr = wn * 64 + nt * 16 + l15;
                const int cb = (ks * 4 + quad) ^ ((rr >> 3) & 7);
                bfr[nt] = *(const half8*)(Bcur + rr * 72 + cb * 8);
            }
#pragma unroll
            for (int mt = 0; mt < 4; ++mt)
#pragma unroll
                for (int nt = 0; nt < 4; ++nt) {
                    ac1[mt][nt] = __builtin_amdgcn_mfma_f32_16x16x32_f16(
                        af1[mt], bfr[nt], ac1[mt][nt], 0, 0, 0);
                    ac2[mt][nt] = __builtin_amdgcn_mfma_f32_16x16x32_f16(
                        af2[mt], bfr[nt], ac2[mt][nt], 0, 0, 0);
                }
        }
        // no trailing barrier: next iter writes the OTHER buffer
    }
    __syncthreads();   // all MFMA reads done before epilogue overwrites Bl
    // GLU -> f16 tile [j][d] (stride 136), then coalesced 16B copy-out
#pragma unroll
    for (int mt = 0; mt < 4; ++mt) {
#pragma unroll
        for (int nt = 0; nt < 4; ++nt) {
            const int dl = wm * 64 + mt * 16 + quad * 4;
            const int jl = wn * 64 + nt * 16 + l15;
            ushort4v p;
#pragma unroll
            for (int r = 0; r < 4; ++r) {
                float a = ac1[mt][nt][r] + bias[m0 + dl + r];
                float gg = ac2[mt][nt][r] + bias[512 + m0 + dl + r];
                p[r] = f2h(a / (1.f + expf(-gg)));
            }
            *(ushort4v*)(Bl + jl * 136 + dl) = p;
        }
    }
    __syncthreads();
    const int r2 = tid >> 1, hh = tid & 1;
    const unsigned short* srcp = Bl + r2 * 136 + hh * 64;
    unsigned short* dstp = g_out + (size_t)(j0 + r2) * 512 + m0 + hh * 64;
#pragma unroll
    for (int q = 0; q < 8; ++q)
        *(intx4*)(dstp + q * 8) = *(const intx4*)(srcp + q * 8);
}

// ------- residual + LayerNorm, fused transposed-f16 output (g, hf both f16) ---------
// 32 j-rows per block, values held in registers (no re-read).
// mode 1: emit hf + ut (512,J) via swizzled LDS transpose; mode 2: emit hb (J,512).
__global__ __launch_bounds__(256, 4) void k_res_ln_t(
    const unsigned short* __restrict__ g, unsigned short* __restrict__ hf,
    unsigned short* __restrict__ ut, unsigned short* __restrict__ hb,
    const float* __restrict__ lng, const float* __restrict__ lnb,
    int layer, int J, int mode) {
    __shared__ unsigned short tile[64 * 40];
    const int tid = threadIdx.x;
    const int r = tid >> 3, sub = tid & 7;          // 32 rows x 8 lanes/row
    const int j0 = blockIdx.x * 32;
    const size_t j = (size_t)j0 + r;
    const unsigned short* gj = g + j * 512;
    unsigned short* hj = hf + j * 512;
    floatx4 v[16];
    float s1 = 0.f, s2 = 0.f;
#pragma unroll
    for (int k = 0; k < 16; ++k) {
        ushort4v gv = *(const ushort4v*)(gj + sub * 4 + k * 32);
        ushort4v hv = *(const ushort4v*)(hj + sub * 4 + k * 32);
        floatx4 vv;
#pragma unroll
        for (int i = 0; i < 4; ++i) vv[i] = h2f(gv[i]) + h2f(hv[i]);  // residual
        v[k] = vv;
        s1 += vv[0] + vv[1] + vv[2] + vv[3];
        s2 += vv[0] * vv[0] + vv[1] * vv[1] + vv[2] * vv[2] + vv[3] * vv[3];
    }
#pragma unroll
    for (int m = 4; m >= 1; m >>= 1) { s1 += __shfl_xor(s1, m, 64); s2 += __shfl_xor(s2, m, 64); }
    const float mu = s1 * (1.f / 512.f);
    const float var = s2 * (1.f / 512.f) - mu * mu;
    const float isd = 1.f / sqrtf(var + 1e-5f);
#pragma unroll
    for (int t = 0; t < 8; ++t) {
        if (mode == 1 && t) __syncthreads();        // protect tile reuse
#pragma unroll
        for (int kk = 0; kk < 2; ++kk) {
            const int k = t * 2 + kk;
            const int cho = sub * 4 + k * 32;       // global ch of elem 0
            floatx4 gw = *(const floatx4*)(lng + layer * 512 + cho);
            floatx4 bw = *(const floatx4*)(lnb + layer * 512 + cho);
            ushort4v p;
#pragma unroll
            for (int i = 0; i < 4; ++i)
                p[i] = f2h((v[k][i] - mu) * isd * gw[i] + bw[i]);
            if (mode == 1) {
                *(ushort4v*)(hj + cho) = p;
                const int chl = kk * 32 + sub * 4;  // ch-local within 64-ch tile
#pragma unroll
                for (int i = 0; i < 4; ++i)
                    tile[(chl + i) * 40 + (r ^ ((((chl + i) >> 2) & 3) << 3))] = p[i];
            } else {
                *(ushort4v*)(hb + j * 512 + cho) = p;
            }
        }
        if (mode == 1) {
            __syncthreads();
            const int chrow = tid >> 2, part = tid & 3;   // 64 ch rows x 4 parts
            const int pb = part ^ ((chrow >> 2) & 3);     // un-swizzle j-block
            *(intx4*)(ut + (size_t)(t * 64 + chrow) * J + j0 + part * 8) =
                *(const intx4*)(tile + chrow * 40 + pb * 8);
        }
    }
}

extern "C" void kernel_launch(void* const* d_in, const int* in_sizes, int n_in,
                              void* d_out, int out_size, void* d_ws, size_t ws_size,
                              hipStream_t stream) {
    (void)in_sizes; (void)n_in; (void)out_size;
    const float* x      = (const float*)d_in[0];
    const float* W_enc  = (const float*)d_in[1];
    const float* W_dec  = (const float*)d_in[2];
    const float* log_dt = (const float*)d_in[3];
    const float* log_Ar = (const float*)d_in[4];
    const float* A_im   = (const float*)d_in[5];
    const float* C_re   = (const float*)d_in[6];
    const float* C_im   = (const float*)d_in[7];
    const float* Dp     = (const float*)d_in[8];
    const float* W_out  = (const float*)d_in[9];
    const float* b_out  = (const float*)d_in[10];
    const float* ln_g   = (const float*)d_in[11];
    const float* ln_b   = (const float*)d_in[12];

    // fixed ~42MiB (lwc/wt/weights/WA/TT) + per-batch-elem 9MiB (ut 2 + scan 3 + hf 2 + vt 2)
    int C = 16;
    while (C > 8 && (size_t)C * (9ull << 20) + (42ull << 20) > ws_size) C >>= 1;
    const size_t J = (size_t)C * 2048;
    const int Rtot = C * 16;

    char* ws = (char*)d_ws;
    size_t off = 0;
    auto alloc = [&](size_t bytes) { void* p = ws + off; off += (bytes + 255) & ~(size_t)255; return p; };
    float4*         lwc   = (float4*)alloc(4ull * 512 * 32 * 16);
    float2*         wt    = (float2*)alloc(4ull * 512 * 32 * 8);
    unsigned short* wencb = (unsigned short*)alloc(512 * 512 * 2);
    unsigned short* wdecb = (unsigned short*)alloc(512 * 512 * 2);
    unsigned short* woutb = (unsigned short*)alloc(4ull * 1024 * 512 * 2);
    unsigned short* WAb   = (unsigned short*)alloc(512ull * 64 * 128 * 2);   // per-layer
    unsigned short* TTb   = (unsigned short*)alloc(512ull * 128 * 192 * 2);  // per-layer
    unsigned short* ut    = (unsigned short*)alloc(512ull * J * 2);          // (512,J) f16
    char*           scan  = (char*)alloc((size_t)C * (3ull << 20));  // P f32 + S0 f16; g16/xq alias
    unsigned short* hf    = (unsigned short*)alloc(J * 512 * 2);     // h (J,512) f16
    unsigned short* vt    = (unsigned short*)alloc(J * 512 * 2);     // gelu out (512,J); hb alias
    unsigned short* g16   = (unsigned short*)scan;   // GLU out (J,512) f16, 2C MiB <= 3C MiB
    unsigned short* xq    = (unsigned short*)scan;   // dead after encoder GEMM
    unsigned short* hb    = vt;                      // vt dead after layer-3 GLU GEMM
    float*          P     = (float*)scan;            // scan scratch (2C MiB)
    unsigned short* S0u   = (unsigned short*)(scan + (size_t)C * (2ull << 20));

    k_precompute<<<256, 256, 0, stream>>>(log_dt, log_Ar, A_im, C_re, C_im, lwc, wt);
    k_cvt<<<1024, 256, 0, stream>>>(W_enc, wencb, 512 * 512);
    k_cvt<<<1024, 256, 0, stream>>>(W_dec, wdecb, 512 * 512);
    k_cvt<<<8192, 256, 0, stream>>>(W_out, woutb, 4 * 1024 * 512);
    for (int b0 = 0; b0 < 16; b0 += C) {
        k_quant_transpose<<<dim3(32, 8, C), 256, 0, stream>>>(x, xq, b0);
        k_gemm<0><<<dim3(C * 16, 4), 256, 0, stream>>>(wencb, xq, nullptr, hf, ut, (int)J, 0);
        for (int i = 0; i < 4; ++i) {
            k_build_wa<<<512, 64, 0, stream>>>(lwc, WAb, i);
            k_build_T<<<512, 256, 0, stream>>>(lwc, Dp, TTb, i);
            k_stateA<<<dim3(Rtot / 128, 512), 256, 0, stream>>>(WAb, ut, P, (int)J, Rtot);
            k_comb<<<dim3(512, C), 64, 0, stream>>>(P, wt, S0u, i, Rtot);
            k_applyB<<<dim3(Rtot / 128, 512), 256, 0, stream>>>(TTb, ut, S0u, vt, (int)J, Rtot);
            k_gemm_glu<<<dim3(C * 16, 4), 256, 0, stream>>>(
                woutb + (size_t)i * 1024 * 512, vt, b_out + (size_t)i * 1024, g16, (int)J);
            k_res_ln_t<<<(int)(J / 32), 256, 0, stream>>>(
                g16, hf, ut, hb, ln_g, ln_b, i, (int)J, (i == 3) ? 2 : 1);
        }
        k_gemm<2><<<dim3(C * 16, 4), 256, 0, stream>>>(wdecb, hb, (float*)d_out, nullptr, nullptr, (int)J, b0);
    }
}

// Round 9
// 928.753 us; speedup vs baseline: 1.2776x; 1.2776x over previous
//
#include <hip/hip_runtime.h>
#include <cstdint>
#include <cstddef>

typedef __attribute__((ext_vector_type(8))) short short8;
typedef __attribute__((ext_vector_type(8))) _Float16 half8;
typedef __attribute__((ext_vector_type(4))) float floatx4;
typedef __attribute__((ext_vector_type(4))) int intx4;
typedef __attribute__((ext_vector_type(4))) unsigned short ushort4v;

__device__ __forceinline__ unsigned short f2h(float f) {
    union { _Float16 h; unsigned short u; } v;
    v.h = (_Float16)f;
    return v.u;
}
__device__ __forceinline__ float h2f(unsigned short u) {
    union { unsigned short u; _Float16 h; } v;
    v.u = u;
    return (float)v.h;
}
// relu that propagates NaN (fmaxf would silently map NaN->0 and hide bugs)
__device__ __forceinline__ float relu_keepnan(float v) {
    return v > 0.f ? v : (v == v ? 0.f : v);
}

// ---------------- f32 -> f16 weight convert ----------------------------------------
__global__ __launch_bounds__(256) void k_cvt(
    const float* __restrict__ src, unsigned short* __restrict__ dst, int n) {
    int i = blockIdx.x * 256 + threadIdx.x;
    if (i < n) dst[i] = f2h(src[i]);
}

// ------- precompute, laid out [layer][n][ch]:
// lwc = (wre, wim, Re(c2), Im(c2)),  wt = w^128 (segment propagator)
__global__ __launch_bounds__(256) void k_precompute(
    const float* __restrict__ ldt, const float* __restrict__ lar,
    const float* __restrict__ aim, const float* __restrict__ cre,
    const float* __restrict__ cim, float4* __restrict__ lwc,
    float2* __restrict__ wt) {
    int idx = blockIdx.x * 256 + threadIdx.x;      // [4][512][32]
    int i = idx >> 14;
    int h = (idx >> 5) & 511;
    int n = idx & 31;
    float dt = expf(ldt[i * 512 + h]);
    float Are = -expf(lar[idx]);
    float Aim = aim[idx];
    float dre = dt * Are, dim = dt * Aim;
    float e = expf(dre);
    float wre = e * cosf(dim);
    float wim = e * sinf(dim);
    float emr = wre - 1.f, emi = wim;              // expm1(dtA)
    float inv = 1.f / (Are * Are + Aim * Aim);
    float fr = (emr * Are + emi * Aim) * inv;      // expm1(dtA)/A
    float fi = (emi * Are - emr * Aim) * inv;
    float cr = cre[idx], ci = cim[idx];
    float4 o;
    o.x = wre; o.y = wim;
    o.z = 2.f * (cr * fr - ci * fi);               // Re(c2)
    o.w = 2.f * (cr * fi + ci * fr);               // Im(c2)
    int oidx = (i * 32 + n) * 512 + h;             // [layer][n][ch]
    lwc[oidx] = o;
    float ar = wre, ai = wim;                      // w^128 by 7 squarings
#pragma unroll
    for (int k = 0; k < 7; ++k) {
        float nr = ar * ar - ai * ai;
        float ni = 2.f * ar * ai;
        ar = nr; ai = ni;
    }
    wt[oidx] = make_float2(ar, ai);
}

// ---------------- quantize (round-half-even) + transpose (B,C,L)f32 -> (J,C) f16 ----
__global__ __launch_bounds__(256) void k_quant_transpose(
    const float* __restrict__ x, unsigned short* __restrict__ xq, int b0) {
    __shared__ unsigned short tile[64][65];
    const int bg = b0 + blockIdx.z, bl = blockIdx.z;
    const int c0 = blockIdx.y * 64, t0 = blockIdx.x * 64;
    const int tid = threadIdx.x;
#pragma unroll
    for (int it = 0; it < 16; ++it) {
        int idx = it * 256 + tid;
        int r = idx >> 6, cc = idx & 63;
        float f = x[(size_t)(bg * 512 + c0 + r) * 2048 + t0 + cc];
        float q = rintf(f * 64.f) * 0.015625f;     // k/64: exact in f16
        tile[r][cc] = f2h(q);
    }
    __syncthreads();
#pragma unroll
    for (int it = 0; it < 16; ++it) {
        int idx = it * 256 + tid;
        int r = idx >> 6, cc = idx & 63;           // r = t-local, cc = c-local
        xq[(size_t)(bl * 2048 + t0 + r) * 512 + c0 + cc] = tile[cc][r];
    }
}

// ---------------- build WA[h][n2][k] = Re/Im(w^(127-k)) f16 (per layer) -------------
__global__ __launch_bounds__(64) void k_build_wa(
    const float4* __restrict__ lwc, unsigned short* __restrict__ WA, int layer) {
    __shared__ unsigned short Ws[64 * 136];
    const int h = blockIdx.x, tid = threadIdx.x;
    if (tid < 32) {
        float4 v = lwc[((size_t)layer * 32 + tid) * 512 + h];
        float pr = 1.f, pi = 0.f;                  // w^0
        for (int m = 0; m < 128; ++m) {
            Ws[(2 * tid) * 136 + (127 - m)] = f2h(pr);
            Ws[(2 * tid + 1) * 136 + (127 - m)] = f2h(pi);
            float nr = pr * v.x - pi * v.y;
            float ni = pr * v.y + pi * v.x;
            pr = nr; pi = ni;
        }
    }
    __syncthreads();
#pragma unroll
    for (int it = 0; it < 16; ++it) {
        int idx = it * 64 + tid;                   // 1024 chunks of 8
        int r = idx >> 4, c8 = idx & 15;
        *(intx4*)(WA + (size_t)h * 8192 + r * 128 + c8 * 8) =
            *(const intx4*)(Ws + r * 136 + c8 * 8);
    }
}

// ------- build TT[h][t][192] f16 (per layer): [Toeplitz K(t-k)+D | cross c2*w^(t+1)]
__global__ __launch_bounds__(256) void k_build_T(
    const float4* __restrict__ lwc, const float* __restrict__ Dp,
    unsigned short* __restrict__ TT, int layer) {
    __shared__ float Kvs[128];
    __shared__ unsigned short Mxs[128 * 64];
    __shared__ float wr_s[32], wi_s[32], cr_s[32], ci_s[32];
    const int h = blockIdx.x, tid = threadIdx.x;
    if (tid < 32) {
        float4 v = lwc[((size_t)layer * 32 + tid) * 512 + h];
        wr_s[tid] = v.x; wi_s[tid] = v.y; cr_s[tid] = v.z; ci_s[tid] = v.w;
    }
    __syncthreads();
    if (tid < 32) {
        const int n = tid;
        float wre = wr_s[n], wim = wi_s[n];
        float ar = cr_s[n], ai = ci_s[n];          // c2 * w^0
        for (int m = 0; m <= 128; ++m) {
            if (m < 128) {                          // K[m] = sum_n Re(c2 w^m)
                float s = ar;
#pragma unroll
                for (int d = 16; d >= 1; d >>= 1) s += __shfl_xor(s, d, 64);
                if (n == 0) Kvs[m] = s;
            }
            if (m >= 1) {                           // cross row t = m-1 uses w^m
                Mxs[(m - 1) * 64 + 2 * n] = f2h(ar);
                Mxs[(m - 1) * 64 + 2 * n + 1] = f2h(-ai);
            }
            float nr = ar * wre - ai * wim;
            float ni = ar * wim + ai * wre;
            ar = nr; ai = ni;
        }
    }
    __syncthreads();
    const float Dh = Dp[layer * 512 + h];
#pragma unroll
    for (int it = 0; it < 12; ++it) {
        int idx = it * 256 + tid;                  // 3072 chunks of 8
        int t = idx / 24, c8 = idx % 24;
        short8 pack;
#pragma unroll
        for (int q = 0; q < 8; ++q) {
            int k = c8 * 8 + q;
            unsigned short us;
            if (k < 128) {
                float val = (k <= t) ? (Kvs[t - k] + (k == t ? Dh : 0.f)) : 0.f;
                us = f2h(val);
            } else {
                us = Mxs[t * 64 + (k - 128)];
            }
            pack[q] = (short)us;
        }
        *(short8*)(TT + (size_t)h * 24576 + t * 192 + c8 * 8) = pack;
    }
}

// ---------------- f16 MFMA GEMM: C[m,j] = sum_k A[m,k]*Bm[j,k], K=512 ---------------
// grid (j-tiles, m-tiles): same-j blocks are gridDim.x apart (mult of 8) -> same XCD.
// MODE 0: relu -> hf f16 (j,512) AND ut f16 (512,J)   MODE 2: relu -> d_out (B,512,L)
template <int MODE>
__global__ __launch_bounds__(256, 2) void k_gemm(
    const unsigned short* __restrict__ A, const unsigned short* __restrict__ Bm,
    float* __restrict__ of32, unsigned short* __restrict__ o16,
    unsigned short* __restrict__ ut, int J, int b0) {
    __shared__ __align__(16) unsigned short lds[2 * 128 * 72];
    unsigned short* Al = lds;
    unsigned short* Bl = lds + 128 * 72;
    const int tid = threadIdx.x;
    const int m0 = blockIdx.y * 128;
    const int j0 = blockIdx.x * 128;
    const int sub = tid & 7;
    const int row = tid >> 3;
    const unsigned short* Ag = A + (size_t)(m0 + row) * 512 + sub * 8;
    const unsigned short* Bg = Bm + (size_t)(j0 + row) * 512 + sub * 8;
    intx4 ra[4], rb[4];
#pragma unroll
    for (int i = 0; i < 4; ++i) {
        ra[i] = *(const intx4*)(Ag + (size_t)i * 32 * 512);
        rb[i] = *(const intx4*)(Bg + (size_t)i * 32 * 512);
    }
    const int lane = tid & 63;
    const int w = tid >> 6;
    const int wm = w & 1, wn = w >> 1;
    const int l15 = lane & 15, quad = lane >> 4;
    floatx4 acc[4][4] = {};
    for (int kt = 0; kt < 8; ++kt) {
#pragma unroll
        for (int i = 0; i < 4; ++i) {
            *(intx4*)(Al + (row + 32 * i) * 72 + sub * 8) = ra[i];
            *(intx4*)(Bl + (row + 32 * i) * 72 + sub * 8) = rb[i];
        }
        __syncthreads();
        if (kt < 7) {
#pragma unroll
            for (int i = 0; i < 4; ++i) {
                ra[i] = *(const intx4*)(Ag + (size_t)i * 32 * 512 + (kt + 1) * 64);
                rb[i] = *(const intx4*)(Bg + (size_t)i * 32 * 512 + (kt + 1) * 64);
            }
        }
#pragma unroll
        for (int ks = 0; ks < 2; ++ks) {
            half8 af[4], bfr[4];
#pragma unroll
            for (int mt = 0; mt < 4; ++mt)
                af[mt] = *(const half8*)(Al + (wm * 64 + mt * 16 + l15) * 72 + ks * 32 + quad * 8);
#pragma unroll
            for (int nt = 0; nt < 4; ++nt)
                bfr[nt] = *(const half8*)(Bl + (wn * 64 + nt * 16 + l15) * 72 + ks * 32 + quad * 8);
#pragma unroll
            for (int mt = 0; mt < 4; ++mt)
#pragma unroll
                for (int nt = 0; nt < 4; ++nt)
                    acc[mt][nt] = __builtin_amdgcn_mfma_f32_16x16x32_f16(
                        af[mt], bfr[nt], acc[mt][nt], 0, 0, 0);
        }
        __syncthreads();
    }
#pragma unroll
    for (int mt = 0; mt < 4; ++mt) {
#pragma unroll
        for (int nt = 0; nt < 4; ++nt) {
            const int dl = wm * 64 + mt * 16 + quad * 4;       // C/D row = quad*4+reg
            const int jl = wn * 64 + nt * 16 + l15;            // C/D col = lane&15
            floatx4 v = acc[mt][nt];
#pragma unroll
            for (int r = 0; r < 4; ++r) v[r] = relu_keepnan(v[r]);
            if (MODE == 0) {
                ushort4v hv;
#pragma unroll
                for (int r = 0; r < 4; ++r) hv[r] = f2h(v[r]);
                *(ushort4v*)(o16 + (size_t)(j0 + jl) * 512 + m0 + dl) = hv;
                // stage f16 into lds tile [d][j] (stride 136) for the ut transpose
#pragma unroll
                for (int r = 0; r < 4; ++r) lds[(dl + r) * 136 + jl] = hv[r];
            } else {
                const int j = j0 + jl;
                const int bl = j >> 11, t = j & 2047;
#pragma unroll
                for (int r = 0; r < 4; ++r)
                    of32[((size_t)((b0 + bl) * 512 + m0 + dl + r)) * 2048 + t] = v[r];
            }
        }
    }
    if (MODE == 0) {
        __syncthreads();
        const int drow = tid >> 1, hh = tid & 1;
        const unsigned short* srcp = lds + drow * 136 + hh * 64;
        unsigned short* dstp = ut + (size_t)(m0 + drow) * J + j0 + hh * 64;
#pragma unroll
        for (int q = 0; q < 8; ++q)
            *(intx4*)(dstp + q * 8) = *(const intx4*)(srcp + q * 8);
    }
}

// ---------------- phase A GEMM: P[h][n2][r] = sum_k WA[h][n2][k] * ut[h][r][k] -------
__global__ __launch_bounds__(256, 4) void k_stateA(
    const unsigned short* __restrict__ WA, const unsigned short* __restrict__ ut,
    float* __restrict__ P, int J, int Rtot) {
    __shared__ __align__(16) unsigned short Aw[64 * 72];
    __shared__ __align__(16) unsigned short Bw[128 * 72];
    const int tid = threadIdx.x;
    const int h = blockIdx.y;
    const int r0 = blockIdx.x * 128;
    const int sub = tid & 7, row = tid >> 3;
    const unsigned short* Ag = WA + (size_t)h * 8192 + row * 128 + sub * 8;
    const unsigned short* Bg = ut + (size_t)h * J + (size_t)(r0 + row) * 128 + sub * 8;
    intx4 ra[2], rb[4];
    ra[0] = *(const intx4*)(Ag);
    ra[1] = *(const intx4*)(Ag + 32 * 128);
#pragma unroll
    for (int i = 0; i < 4; ++i) rb[i] = *(const intx4*)(Bg + i * 32 * 128);
    const int lane = tid & 63, w = tid >> 6;
    const int wm = w & 1, wn = w >> 1;
    const int l15 = lane & 15, quad = lane >> 4;
    floatx4 acc[2][4] = {};
    for (int kt = 0; kt < 2; ++kt) {
        *(intx4*)(Aw + row * 72 + sub * 8) = ra[0];
        *(intx4*)(Aw + (row + 32) * 72 + sub * 8) = ra[1];
#pragma unroll
        for (int i = 0; i < 4; ++i)
            *(intx4*)(Bw + (row + 32 * i) * 72 + sub * 8) = rb[i];
        __syncthreads();
        if (kt == 0) {
            ra[0] = *(const intx4*)(Ag + 64);
            ra[1] = *(const intx4*)(Ag + 32 * 128 + 64);
#pragma unroll
            for (int i = 0; i < 4; ++i) rb[i] = *(const intx4*)(Bg + i * 32 * 128 + 64);
        }
#pragma unroll
        for (int ks = 0; ks < 2; ++ks) {
            half8 af[2], bfr[4];
#pragma unroll
            for (int mt = 0; mt < 2; ++mt)
                af[mt] = *(const half8*)(Aw + (wm * 32 + mt * 16 + l15) * 72 + ks * 32 + quad * 8);
#pragma unroll
            for (int nt = 0; nt < 4; ++nt)
                bfr[nt] = *(const half8*)(Bw + (wn * 64 + nt * 16 + l15) * 72 + ks * 32 + quad * 8);
#pragma unroll
            for (int mt = 0; mt < 2; ++mt)
#pragma unroll
                for (int nt = 0; nt < 4; ++nt)
                    acc[mt][nt] = __builtin_amdgcn_mfma_f32_16x16x32_f16(
                        af[mt], bfr[nt], acc[mt][nt], 0, 0, 0);
        }
        __syncthreads();
    }
#pragma unroll
    for (int mt = 0; mt < 2; ++mt)
#pragma unroll
        for (int nt = 0; nt < 4; ++nt)
#pragma unroll
            for (int r = 0; r < 4; ++r)
                P[((size_t)h * 64 + wm * 32 + mt * 16 + quad * 4 + r) * Rtot +
                  r0 + wn * 64 + nt * 16 + l15] = acc[mt][nt][r];
}

// ---------------- combine: S0[h][r][n2] f16, exclusive prefix over 16 segments -------
__global__ __launch_bounds__(64) void k_comb(
    const float* __restrict__ P, const float2* __restrict__ wt,
    unsigned short* __restrict__ S0, int layer, int Rtot) {
    __shared__ float Ps[64][17];
    __shared__ unsigned short S0s[16][64];
    const int h = blockIdx.x, bl = blockIdx.y;
    const int tid = threadIdx.x;
#pragma unroll
    for (int it = 0; it < 4; ++it) {
        int idx = it * 64 + tid;                   // 256 float4
        int n2 = idx >> 2, pt = idx & 3;
        float4 v = *(const float4*)(P + ((size_t)h * 64 + n2) * Rtot + bl * 16 + pt * 4);
        Ps[n2][pt * 4 + 0] = v.x; Ps[n2][pt * 4 + 1] = v.y;
        Ps[n2][pt * 4 + 2] = v.z; Ps[n2][pt * 4 + 3] = v.w;
    }
    __syncthreads();
    if (tid < 32) {
        const int n = tid;
        float2 wv = wt[((size_t)layer * 32 + n) * 512 + h];
        float ar = 0.f, ai = 0.f;
        for (int g = 0; g < 16; ++g) {
            S0s[g][2 * n] = f2h(ar);
            S0s[g][2 * n + 1] = f2h(ai);
            float pr = Ps[2 * n][g], pi = Ps[2 * n + 1][g];
            float nr = fmaf(wv.x, ar, fmaf(-wv.y, ai, pr));
            float ni = fmaf(wv.x, ai, fmaf(wv.y, ar, pi));
            ar = nr; ai = ni;
        }
    }
    __syncthreads();
    const int g = tid >> 2, pt = tid & 3;
    unsigned short* dst = S0 + ((size_t)h * Rtot + bl * 16 + g) * 64 + pt * 16;
    *(intx4*)(dst) = *(const intx4*)(&S0s[g][pt * 16]);
    *(intx4*)(dst + 8) = *(const intx4*)(&S0s[g][pt * 16 + 8]);
}

// ---------------- phase B GEMM + gelu: vt[h][r*128+t] = gelu(sum_k TT[t][k]*[ut|S0]) -
__global__ __launch_bounds__(256, 2) void k_applyB(
    const unsigned short* __restrict__ TT, const unsigned short* __restrict__ ut,
    const unsigned short* __restrict__ S0, unsigned short* __restrict__ vt,
    int J, int Rtot) {
    __shared__ __align__(16) unsigned short lds[2 * 128 * 72];
    unsigned short* Al = lds;
    unsigned short* Bl = lds + 128 * 72;
    const int tid = threadIdx.x;
    const int h = blockIdx.y;
    const int r0 = blockIdx.x * 128;
    const int sub = tid & 7, row = tid >> 3;
    const unsigned short* Ag = TT + (size_t)h * 24576 + row * 192 + sub * 8;
    const unsigned short* Bu = ut + (size_t)h * J + (size_t)(r0 + row) * 128 + sub * 8;
    const unsigned short* Bs = S0 + ((size_t)h * Rtot + r0 + row) * 64 + sub * 8;
    intx4 ra[4], rb[4];
#pragma unroll
    for (int i = 0; i < 4; ++i) {
        ra[i] = *(const intx4*)(Ag + i * 32 * 192);
        rb[i] = *(const intx4*)(Bu + i * 32 * 128);
    }
    const int lane = tid & 63, w = tid >> 6;
    const int wm = w & 1, wn = w >> 1;
    const int l15 = lane & 15, quad = lane >> 4;
    floatx4 acc[4][4] = {};
    for (int kt = 0; kt < 3; ++kt) {
#pragma unroll
        for (int i = 0; i < 4; ++i) {
            *(intx4*)(Al + (row + 32 * i) * 72 + sub * 8) = ra[i];
            *(intx4*)(Bl + (row + 32 * i) * 72 + sub * 8) = rb[i];
        }
        __syncthreads();
        if (kt == 0) {
#pragma unroll
            for (int i = 0; i < 4; ++i) {
                ra[i] = *(const intx4*)(Ag + i * 32 * 192 + 64);
                rb[i] = *(const intx4*)(Bu + i * 32 * 128 + 64);
            }
        } else if (kt == 1) {
#pragma unroll
            for (int i = 0; i < 4; ++i) {
                ra[i] = *(const intx4*)(Ag + i * 32 * 192 + 128);
                rb[i] = *(const intx4*)(Bs + i * 32 * 64);
            }
        }
#pragma unroll
        for (int ks = 0; ks < 2; ++ks) {
            half8 af[4], bfr[4];
#pragma unroll
            for (int mt = 0; mt < 4; ++mt)
                af[mt] = *(const half8*)(Al + (wm * 64 + mt * 16 + l15) * 72 + ks * 32 + quad * 8);
#pragma unroll
            for (int nt = 0; nt < 4; ++nt)
                bfr[nt] = *(const half8*)(Bl + (wn * 64 + nt * 16 + l15) * 72 + ks * 32 + quad * 8);
#pragma unroll
            for (int mt = 0; mt < 4; ++mt)
#pragma unroll
                for (int nt = 0; nt < 4; ++nt)
                    acc[mt][nt] = __builtin_amdgcn_mfma_f32_16x16x32_f16(
                        af[mt], bfr[nt], acc[mt][nt], 0, 0, 0);
        }
        __syncthreads();
    }
    // epilogue: gelu -> f16, LDS tile [r][t] (stride 136), then coalesced copy-out
#pragma unroll
    for (int mt = 0; mt < 4; ++mt)
#pragma unroll
        for (int nt = 0; nt < 4; ++nt) {
            const int tl = wm * 64 + mt * 16 + quad * 4;   // D row = t
            const int rl = wn * 64 + nt * 16 + l15;        // D col = r
            ushort4v pack;
#pragma unroll
            for (int r = 0; r < 4; ++r) {
                float y = acc[mt][nt][r];
                float ge = 0.5f * y * (1.f + erff(y * 0.70710678118654752f));
                pack[r] = f2h(ge);
            }
            *(ushort4v*)(lds + rl * 136 + tl) = pack;
        }
    __syncthreads();
    const int rl2 = tid >> 1, hh = tid & 1;
    const unsigned short* srcp = lds + rl2 * 136 + hh * 64;
    unsigned short* dstp = vt + (size_t)h * J + (size_t)(r0 + rl2) * 128 + hh * 64;
#pragma unroll
    for (int q = 0; q < 8; ++q)
        *(intx4*)(dstp + q * 8) = *(const intx4*)(srcp + q * 8);
}

// ------- fused W_out GEMM + GLU: g_out[j,d] = (a+b1)*sigmoid(g+b2), f16 out ----------
// Main loop = R6-proven (A/B LDS-staged, stride-72, XOR-swizzled B pack, 2 barriers/kt,
// prefetch between barrier and MFMAs; measured 60us). Epilogue = R7-proven f16 LDS
// transpose -> coalesced 16B stores (WRITE 74->35MB; f16 8B scattered stores cost +20us).
__global__ __launch_bounds__(256, 2) void k_gemm_glu(
    const unsigned short* __restrict__ A,   // W_out layer (1024,512) f16
    const unsigned short* __restrict__ Bt,  // vt (512, J) f16
    const float* __restrict__ bias,         // b_out layer (1024) f32
    unsigned short* __restrict__ g_out, int J) {  // (J,512) f16
    __shared__ __align__(16) unsigned short lds[3 * 128 * 72];
    unsigned short* A1l = lds;
    unsigned short* A2l = lds + 9216;
    unsigned short* Bl  = lds + 18432;
    const int tid = threadIdx.x;
    const int m0 = blockIdx.y * 128;
    const int j0 = blockIdx.x * 128;
    const int sub = tid & 7;
    const int row = tid >> 3;                        // 0..31
    const unsigned short* A1g = A + (size_t)(m0 + row) * 512 + sub * 8;
    const unsigned short* A2g = A1g + 512 * 512;
    // B staging map: channel pair (2*chp, 2*chp+1) chp 0..31, j-octets jo and jo+8
    const int chp = tid >> 3, jo = tid & 7;
    const unsigned short* Bg = Bt + (size_t)(2 * chp) * J + j0 + jo * 8;
    intx4 ra1[4], ra2[4], rb[4];
#pragma unroll
    for (int i = 0; i < 4; ++i) {
        ra1[i] = *(const intx4*)(A1g + (size_t)i * 32 * 512);
        ra2[i] = *(const intx4*)(A2g + (size_t)i * 32 * 512);
    }
    rb[0] = *(const intx4*)(Bg);
    rb[1] = *(const intx4*)(Bg + J);
    rb[2] = *(const intx4*)(Bg + 64);
    rb[3] = *(const intx4*)(Bg + J + 64);
    const int lane = tid & 63;
    const int w = tid >> 6;
    const int wm = w & 1, wn = w >> 1;               // 2x2 waves: m 2x64, n 2x64
    const int l15 = lane & 15, quad = lane >> 4;
    // swizzled column base for B writes: colblk' = (chp>>2) ^ ((j>>3)&7)
    const int colbase = (((chp >> 2) ^ jo) << 3) + (chp & 3) * 2;
    floatx4 ac1[4][4] = {}, ac2[4][4] = {};
    for (int kt = 0; kt < 8; ++kt) {
#pragma unroll
        for (int i = 0; i < 4; ++i) {
            *(intx4*)(A1l + (row + 32 * i) * 72 + sub * 8) = ra1[i];
            *(intx4*)(A2l + (row + 32 * i) * 72 + sub * 8) = ra2[i];
        }
        // B: pack channel pair into u32 words, write (j, chpair) with XOR-swizzle.
        // j-octets jo*8.. and (jo+8)*8..: (j>>3)&7 == jo for both -> same colbase.
        {
            unsigned int* B32 = (unsigned int*)Bl;
#pragma unroll
            for (int half = 0; half < 2; ++half) {
                const int jb = (jo + half * 8) * 8;
                intx4 e0 = rb[half * 2], e1 = rb[half * 2 + 1];
#pragma unroll
                for (int i = 0; i < 4; ++i) {
                    unsigned int ae = (unsigned int)e0[i], be = (unsigned int)e1[i];
                    unsigned int lo = (ae & 0xffffu) | (be << 16);        // j = jb+2i
                    unsigned int hi = (ae >> 16) | (be & 0xffff0000u);    // j = jb+2i+1
                    B32[((jb + 2 * i) * 72 + colbase) >> 1] = lo;
                    B32[((jb + 2 * i + 1) * 72 + colbase) >> 1] = hi;
                }
            }
        }
        __syncthreads();
        if (kt < 7) {
#pragma unroll
            for (int i = 0; i < 4; ++i) {
                ra1[i] = *(const intx4*)(A1g + (size_t)i * 32 * 512 + (kt + 1) * 64);
                ra2[i] = *(const intx4*)(A2g + (size_t)i * 32 * 512 + (kt + 1) * 64);
            }
            rb[0] = *(const intx4*)(Bg + (size_t)(kt + 1) * 64 * J);
            rb[1] = *(const intx4*)(Bg + (size_t)(kt + 1) * 64 * J + J);
            rb[2] = *(const intx4*)(Bg + (size_t)(kt + 1) * 64 * J + 64);
            rb[3] = *(const intx4*)(Bg + (size_t)(kt + 1) * 64 * J + J + 64);
        }
#pragma unroll
        for (int ks = 0; ks < 2; ++ks) {
            half8 af1[4], af2[4], bfr[4];
#pragma unroll
            for (int mt = 0; mt < 4; ++mt) {
                af1[mt] = *(const half8*)(A1l + (wm * 64 + mt * 16 + l15) * 72 + ks * 32 + quad * 8);
                af2[mt] = *(const half8*)(A2l + (wm * 64 + mt * 16 + l15) * 72 + ks * 32 + quad * 8);
            }
#pragma unroll
            for (int nt = 0; nt < 4; ++nt) {
                const int rr = wn * 64 + nt * 16 + l15;
                const int cb = (ks * 4 + quad) ^ ((rr >> 3) & 7);
                bfr[nt] = *(const half8*)(Bl + rr * 72 + cb * 8);
            }
#pragma unroll
            for (int mt = 0; mt < 4; ++mt)
#pragma unroll
                for (int nt = 0; nt < 4; ++nt) {
                    ac1[mt][nt] = __builtin_amdgcn_mfma_f32_16x16x32_f16(
                        af1[mt], bfr[nt], ac1[mt][nt], 0, 0, 0);
                    ac2[mt][nt] = __builtin_amdgcn_mfma_f32_16x16x32_f16(
                        af2[mt], bfr[nt], ac2[mt][nt], 0, 0, 0);
                }
        }
        __syncthreads();
    }
    // epilogue: GLU -> f16 tile [j][d] (stride 136, reuses A1l+A2l region: 17408 < 18432),
    // then coalesced 16B copy-out. Loop's trailing barrier fences the LDS reuse.
#pragma unroll
    for (int mt = 0; mt < 4; ++mt) {
#pragma unroll
        for (int nt = 0; nt < 4; ++nt) {
            const int dl = wm * 64 + mt * 16 + quad * 4;
            const int jl = wn * 64 + nt * 16 + l15;
            ushort4v p;
#pragma unroll
            for (int r = 0; r < 4; ++r) {
                float a = ac1[mt][nt][r] + bias[m0 + dl + r];
                float gg = ac2[mt][nt][r] + bias[512 + m0 + dl + r];
                p[r] = f2h(a / (1.f + expf(-gg)));
            }
            *(ushort4v*)(lds + jl * 136 + dl) = p;
        }
    }
    __syncthreads();
    const int r2 = tid >> 1, hh = tid & 1;
    const unsigned short* srcp = lds + r2 * 136 + hh * 64;
    unsigned short* dstp = g_out + (size_t)(j0 + r2) * 512 + m0 + hh * 64;
#pragma unroll
    for (int q = 0; q < 8; ++q)
        *(intx4*)(dstp + q * 8) = *(const intx4*)(srcp + q * 8);
}

// ------- residual + LayerNorm, fused transposed-f16 output (g, hf both f16) ---------
// 32 j-rows per block, values held in registers (no re-read).
// mode 1: emit hf + ut (512,J) via swizzled LDS transpose; mode 2: emit hb (J,512).
__global__ __launch_bounds__(256, 4) void k_res_ln_t(
    const unsigned short* __restrict__ g, unsigned short* __restrict__ hf,
    unsigned short* __restrict__ ut, unsigned short* __restrict__ hb,
    const float* __restrict__ lng, const float* __restrict__ lnb,
    int layer, int J, int mode) {
    __shared__ unsigned short tile[64 * 40];
    const int tid = threadIdx.x;
    const int r = tid >> 3, sub = tid & 7;          // 32 rows x 8 lanes/row
    const int j0 = blockIdx.x * 32;
    const size_t j = (size_t)j0 + r;
    const unsigned short* gj = g + j * 512;
    unsigned short* hj = hf + j * 512;
    floatx4 v[16];
    float s1 = 0.f, s2 = 0.f;
#pragma unroll
    for (int k = 0; k < 16; ++k) {
        ushort4v gv = *(const ushort4v*)(gj + sub * 4 + k * 32);
        ushort4v hv = *(const ushort4v*)(hj + sub * 4 + k * 32);
        floatx4 vv;
#pragma unroll
        for (int i = 0; i < 4; ++i) vv[i] = h2f(gv[i]) + h2f(hv[i]);  // residual
        v[k] = vv;
        s1 += vv[0] + vv[1] + vv[2] + vv[3];
        s2 += vv[0] * vv[0] + vv[1] * vv[1] + vv[2] * vv[2] + vv[3] * vv[3];
    }
#pragma unroll
    for (int m = 4; m >= 1; m >>= 1) { s1 += __shfl_xor(s1, m, 64); s2 += __shfl_xor(s2, m, 64); }
    const float mu = s1 * (1.f / 512.f);
    const float var = s2 * (1.f / 512.f) - mu * mu;
    const float isd = 1.f / sqrtf(var + 1e-5f);
#pragma unroll
    for (int t = 0; t < 8; ++t) {
        if (mode == 1 && t) __syncthreads();        // protect tile reuse
#pragma unroll
        for (int kk = 0; kk < 2; ++kk) {
            const int k = t * 2 + kk;
            const int cho = sub * 4 + k * 32;       // global ch of elem 0
            floatx4 gw = *(const floatx4*)(lng + layer * 512 + cho);
            floatx4 bw = *(const floatx4*)(lnb + layer * 512 + cho);
            ushort4v p;
#pragma unroll
            for (int i = 0; i < 4; ++i)
                p[i] = f2h((v[k][i] - mu) * isd * gw[i] + bw[i]);
            if (mode == 1) {
                *(ushort4v*)(hj + cho) = p;
                const int chl = kk * 32 + sub * 4;  // ch-local within 64-ch tile
#pragma unroll
                for (int i = 0; i < 4; ++i)
                    tile[(chl + i) * 40 + (r ^ ((((chl + i) >> 2) & 3) << 3))] = p[i];
            } else {
                *(ushort4v*)(hb + j * 512 + cho) = p;
            }
        }
        if (mode == 1) {
            __syncthreads();
            const int chrow = tid >> 2, part = tid & 3;   // 64 ch rows x 4 parts
            const int pb = part ^ ((chrow >> 2) & 3);     // un-swizzle j-block
            *(intx4*)(ut + (size_t)(t * 64 + chrow) * J + j0 + part * 8) =
                *(const intx4*)(tile + chrow * 40 + pb * 8);
        }
    }
}

extern "C" void kernel_launch(void* const* d_in, const int* in_sizes, int n_in,
                              void* d_out, int out_size, void* d_ws, size_t ws_size,
                              hipStream_t stream) {
    (void)in_sizes; (void)n_in; (void)out_size;
    const float* x      = (const float*)d_in[0];
    const float* W_enc  = (const float*)d_in[1];
    const float* W_dec  = (const float*)d_in[2];
    const float* log_dt = (const float*)d_in[3];
    const float* log_Ar = (const float*)d_in[4];
    const float* A_im   = (const float*)d_in[5];
    const float* C_re   = (const float*)d_in[6];
    const float* C_im   = (const float*)d_in[7];
    const float* Dp     = (const float*)d_in[8];
    const float* W_out  = (const float*)d_in[9];
    const float* b_out  = (const float*)d_in[10];
    const float* ln_g   = (const float*)d_in[11];
    const float* ln_b   = (const float*)d_in[12];

    // fixed ~42MiB (lwc/wt/weights/WA/TT) + per-batch-elem 9MiB (ut 2 + scan 3 + hf 2 + vt 2)
    int C = 16;
    while (C > 8 && (size_t)C * (9ull << 20) + (42ull << 20) > ws_size) C >>= 1;
    const size_t J = (size_t)C * 2048;
    const int Rtot = C * 16;

    char* ws = (char*)d_ws;
    size_t off = 0;
    auto alloc = [&](size_t bytes) { void* p = ws + off; off += (bytes + 255) & ~(size_t)255; return p; };
    float4*         lwc   = (float4*)alloc(4ull * 512 * 32 * 16);
    float2*         wt    = (float2*)alloc(4ull * 512 * 32 * 8);
    unsigned short* wencb = (unsigned short*)alloc(512 * 512 * 2);
    unsigned short* wdecb = (unsigned short*)alloc(512 * 512 * 2);
    unsigned short* woutb = (unsigned short*)alloc(4ull * 1024 * 512 * 2);
    unsigned short* WAb   = (unsigned short*)alloc(512ull * 64 * 128 * 2);   // per-layer
    unsigned short* TTb   = (unsigned short*)alloc(512ull * 128 * 192 * 2);  // per-layer
    unsigned short* ut    = (unsigned short*)alloc(512ull * J * 2);          // (512,J) f16
    char*           scan  = (char*)alloc((size_t)C * (3ull << 20));  // P f32 + S0 f16; g16/xq alias
    unsigned short* hf    = (unsigned short*)alloc(J * 512 * 2);     // h (J,512) f16
    unsigned short* vt    = (unsigned short*)alloc(J * 512 * 2);     // gelu out (512,J); hb alias
    unsigned short* g16   = (unsigned short*)scan;   // GLU out (J,512) f16, 2C MiB <= 3C MiB
    unsigned short* xq    = (unsigned short*)scan;   // dead after encoder GEMM
    unsigned short* hb    = vt;                      // vt dead after layer-3 GLU GEMM
    float*          P     = (float*)scan;            // scan scratch (2C MiB)
    unsigned short* S0u   = (unsigned short*)(scan + (size_t)C * (2ull << 20));

    k_precompute<<<256, 256, 0, stream>>>(log_dt, log_Ar, A_im, C_re, C_im, lwc, wt);
    k_cvt<<<1024, 256, 0, stream>>>(W_enc, wencb, 512 * 512);
    k_cvt<<<1024, 256, 0, stream>>>(W_dec, wdecb, 512 * 512);
    k_cvt<<<8192, 256, 0, stream>>>(W_out, woutb, 4 * 1024 * 512);
    for (int b0 = 0; b0 < 16; b0 += C) {
        k_quant_transpose<<<dim3(32, 8, C), 256, 0, stream>>>(x, xq, b0);
        k_gemm<0><<<dim3(C * 16, 4), 256, 0, stream>>>(wencb, xq, nullptr, hf, ut, (int)J, 0);
        for (int i = 0; i < 4; ++i) {
            k_build_wa<<<512, 64, 0, stream>>>(lwc, WAb, i);
            k_build_T<<<512, 256, 0, stream>>>(lwc, Dp, TTb, i);
            k_stateA<<<dim3(Rtot / 128, 512), 256, 0, stream>>>(WAb, ut, P, (int)J, Rtot);
            k_comb<<<dim3(512, C), 64, 0, stream>>>(P, wt, S0u, i, Rtot);
            k_applyB<<<dim3(Rtot / 128, 512), 256, 0, stream>>>(TTb, ut, S0u, vt, (int)J, Rtot);
            k_gemm_glu<<<dim3(C * 16, 4), 256, 0, stream>>>(
                woutb + (size_t)i * 1024 * 512, vt, b_out + (size_t)i * 1024, g16, (int)J);
            k_res_ln_t<<<(int)(J / 32), 256, 0, stream>>>(
                g16, hf, ut, hb, ln_g, ln_b, i, (int)J, (i == 3) ? 2 : 1);
        }
        k_gemm<2><<<dim3(C * 16, 4), 256, 0, stream>>>(wdecb, hb, (float*)d_out, nullptr, nullptr, (int)J, b0);
    }
}

// Round 10
// 873.954 us; speedup vs baseline: 1.3577x; 1.0627x over previous
//
#include <hip/hip_runtime.h>
#include <cstdint>
#include <cstddef>

typedef __attribute__((ext_vector_type(8))) short short8;
typedef __attribute__((ext_vector_type(8))) _Float16 half8;
typedef __attribute__((ext_vector_type(4))) float floatx4;
typedef __attribute__((ext_vector_type(4))) int intx4;
typedef __attribute__((ext_vector_type(4))) unsigned short ushort4v;

__device__ __forceinline__ unsigned short f2h(float f) {
    union { _Float16 h; unsigned short u; } v;
    v.h = (_Float16)f;
    return v.u;
}
__device__ __forceinline__ float h2f(unsigned short u) {
    union { unsigned short u; _Float16 h; } v;
    v.u = u;
    return (float)v.h;
}
// relu that propagates NaN (fmaxf would silently map NaN->0 and hide bugs)
__device__ __forceinline__ float relu_keepnan(float v) {
    return v > 0.f ? v : (v == v ? 0.f : v);
}

// ---------------- f32 -> f16 weight convert ----------------------------------------
__global__ __launch_bounds__(256) void k_cvt(
    const float* __restrict__ src, unsigned short* __restrict__ dst, int n) {
    int i = blockIdx.x * 256 + threadIdx.x;
    if (i < n) dst[i] = f2h(src[i]);
}

// ------- precompute, laid out [layer][n][ch]:
// lwc = (wre, wim, Re(c2), Im(c2)),  wt = w^128 (segment propagator)
__global__ __launch_bounds__(256) void k_precompute(
    const float* __restrict__ ldt, const float* __restrict__ lar,
    const float* __restrict__ aim, const float* __restrict__ cre,
    const float* __restrict__ cim, float4* __restrict__ lwc,
    float2* __restrict__ wt) {
    int idx = blockIdx.x * 256 + threadIdx.x;      // [4][512][32]
    int i = idx >> 14;
    int h = (idx >> 5) & 511;
    int n = idx & 31;
    float dt = expf(ldt[i * 512 + h]);
    float Are = -expf(lar[idx]);
    float Aim = aim[idx];
    float dre = dt * Are, dim = dt * Aim;
    float e = expf(dre);
    float wre = e * cosf(dim);
    float wim = e * sinf(dim);
    float emr = wre - 1.f, emi = wim;              // expm1(dtA)
    float inv = 1.f / (Are * Are + Aim * Aim);
    float fr = (emr * Are + emi * Aim) * inv;      // expm1(dtA)/A
    float fi = (emi * Are - emr * Aim) * inv;
    float cr = cre[idx], ci = cim[idx];
    float4 o;
    o.x = wre; o.y = wim;
    o.z = 2.f * (cr * fr - ci * fi);               // Re(c2)
    o.w = 2.f * (cr * fi + ci * fr);               // Im(c2)
    int oidx = (i * 32 + n) * 512 + h;             // [layer][n][ch]
    lwc[oidx] = o;
    float ar = wre, ai = wim;                      // w^128 by 7 squarings
#pragma unroll
    for (int k = 0; k < 7; ++k) {
        float nr = ar * ar - ai * ai;
        float ni = 2.f * ar * ai;
        ar = nr; ai = ni;
    }
    wt[oidx] = make_float2(ar, ai);
}

// ---------------- quantize (round-half-even) + transpose (B,C,L)f32 -> (J,C) f16 ----
__global__ __launch_bounds__(256) void k_quant_transpose(
    const float* __restrict__ x, unsigned short* __restrict__ xq, int b0) {
    __shared__ unsigned short tile[64][65];
    const int bg = b0 + blockIdx.z, bl = blockIdx.z;
    const int c0 = blockIdx.y * 64, t0 = blockIdx.x * 64;
    const int tid = threadIdx.x;
#pragma unroll
    for (int it = 0; it < 16; ++it) {
        int idx = it * 256 + tid;
        int r = idx >> 6, cc = idx & 63;
        float f = x[(size_t)(bg * 512 + c0 + r) * 2048 + t0 + cc];
        float q = rintf(f * 64.f) * 0.015625f;     // k/64: exact in f16
        tile[r][cc] = f2h(q);
    }
    __syncthreads();
#pragma unroll
    for (int it = 0; it < 16; ++it) {
        int idx = it * 256 + tid;
        int r = idx >> 6, cc = idx & 63;           // r = t-local, cc = c-local
        xq[(size_t)(bl * 2048 + t0 + r) * 512 + c0 + cc] = tile[cc][r];
    }
}

// ---------------- build WA[h][n2][k] = Re/Im(w^(127-k)) f16 (per layer) -------------
__global__ __launch_bounds__(64) void k_build_wa(
    const float4* __restrict__ lwc, unsigned short* __restrict__ WA, int layer) {
    __shared__ unsigned short Ws[64 * 136];
    const int h = blockIdx.x, tid = threadIdx.x;
    if (tid < 32) {
        float4 v = lwc[((size_t)layer * 32 + tid) * 512 + h];
        float pr = 1.f, pi = 0.f;                  // w^0
        for (int m = 0; m < 128; ++m) {
            Ws[(2 * tid) * 136 + (127 - m)] = f2h(pr);
            Ws[(2 * tid + 1) * 136 + (127 - m)] = f2h(pi);
            float nr = pr * v.x - pi * v.y;
            float ni = pr * v.y + pi * v.x;
            pr = nr; pi = ni;
        }
    }
    __syncthreads();
#pragma unroll
    for (int it = 0; it < 16; ++it) {
        int idx = it * 64 + tid;                   // 1024 chunks of 8
        int r = idx >> 4, c8 = idx & 15;
        *(intx4*)(WA + (size_t)h * 8192 + r * 128 + c8 * 8) =
            *(const intx4*)(Ws + r * 136 + c8 * 8);
    }
}

// ------- build TT[h][t][192] f16 (per layer): [Toeplitz K(t-k)+D | cross c2*w^(t+1)]
__global__ __launch_bounds__(256) void k_build_T(
    const float4* __restrict__ lwc, const float* __restrict__ Dp,
    unsigned short* __restrict__ TT, int layer) {
    __shared__ float Kvs[128];
    __shared__ unsigned short Mxs[128 * 64];
    __shared__ float wr_s[32], wi_s[32], cr_s[32], ci_s[32];
    const int h = blockIdx.x, tid = threadIdx.x;
    if (tid < 32) {
        float4 v = lwc[((size_t)layer * 32 + tid) * 512 + h];
        wr_s[tid] = v.x; wi_s[tid] = v.y; cr_s[tid] = v.z; ci_s[tid] = v.w;
    }
    __syncthreads();
    if (tid < 32) {
        const int n = tid;
        float wre = wr_s[n], wim = wi_s[n];
        float ar = cr_s[n], ai = ci_s[n];          // c2 * w^0
        for (int m = 0; m <= 128; ++m) {
            if (m < 128) {                          // K[m] = sum_n Re(c2 w^m)
                float s = ar;
#pragma unroll
                for (int d = 16; d >= 1; d >>= 1) s += __shfl_xor(s, d, 64);
                if (n == 0) Kvs[m] = s;
            }
            if (m >= 1) {                           // cross row t = m-1 uses w^m
                Mxs[(m - 1) * 64 + 2 * n] = f2h(ar);
                Mxs[(m - 1) * 64 + 2 * n + 1] = f2h(-ai);
            }
            float nr = ar * wre - ai * wim;
            float ni = ar * wim + ai * wre;
            ar = nr; ai = ni;
        }
    }
    __syncthreads();
    const float Dh = Dp[layer * 512 + h];
#pragma unroll
    for (int it = 0; it < 12; ++it) {
        int idx = it * 256 + tid;                  // 3072 chunks of 8
        int t = idx / 24, c8 = idx % 24;
        short8 pack;
#pragma unroll
        for (int q = 0; q < 8; ++q) {
            int k = c8 * 8 + q;
            unsigned short us;
            if (k < 128) {
                float val = (k <= t) ? (Kvs[t - k] + (k == t ? Dh : 0.f)) : 0.f;
                us = f2h(val);
            } else {
                us = Mxs[t * 64 + (k - 128)];
            }
            pack[q] = (short)us;
        }
        *(short8*)(TT + (size_t)h * 24576 + t * 192 + c8 * 8) = pack;
    }
}

// ---------------- f16 MFMA GEMM: C[m,j] = sum_k A[m,k]*Bm[j,k], K=512 ---------------
// grid (j-tiles, m-tiles): same-j blocks are gridDim.x apart (mult of 8) -> same XCD.
// MODE 0: relu -> hf f16 (j,512) AND ut f16 (512,J)   MODE 2: relu -> d_out (B,512,L)
template <int MODE>
__global__ __launch_bounds__(256, 3) void k_gemm(
    const unsigned short* __restrict__ A, const unsigned short* __restrict__ Bm,
    float* __restrict__ of32, unsigned short* __restrict__ o16,
    unsigned short* __restrict__ ut, int J, int b0) {
    __shared__ __align__(16) unsigned short lds[2 * 128 * 72];
    unsigned short* Al = lds;
    unsigned short* Bl = lds + 128 * 72;
    const int tid = threadIdx.x;
    const int m0 = blockIdx.y * 128;
    const int j0 = blockIdx.x * 128;
    const int sub = tid & 7;
    const int row = tid >> 3;
    const unsigned short* Ag = A + (size_t)(m0 + row) * 512 + sub * 8;
    const unsigned short* Bg = Bm + (size_t)(j0 + row) * 512 + sub * 8;
    intx4 ra[4], rb[4];
#pragma unroll
    for (int i = 0; i < 4; ++i) {
        ra[i] = *(const intx4*)(Ag + (size_t)i * 32 * 512);
        rb[i] = *(const intx4*)(Bg + (size_t)i * 32 * 512);
    }
    const int lane = tid & 63;
    const int w = tid >> 6;
    const int wm = w & 1, wn = w >> 1;
    const int l15 = lane & 15, quad = lane >> 4;
    floatx4 acc[4][4] = {};
    for (int kt = 0; kt < 8; ++kt) {
#pragma unroll
        for (int i = 0; i < 4; ++i) {
            *(intx4*)(Al + (row + 32 * i) * 72 + sub * 8) = ra[i];
            *(intx4*)(Bl + (row + 32 * i) * 72 + sub * 8) = rb[i];
        }
        __syncthreads();
        if (kt < 7) {
#pragma unroll
            for (int i = 0; i < 4; ++i) {
                ra[i] = *(const intx4*)(Ag + (size_t)i * 32 * 512 + (kt + 1) * 64);
                rb[i] = *(const intx4*)(Bg + (size_t)i * 32 * 512 + (kt + 1) * 64);
            }
        }
#pragma unroll
        for (int ks = 0; ks < 2; ++ks) {
            half8 af[4], bfr[4];
#pragma unroll
            for (int mt = 0; mt < 4; ++mt)
                af[mt] = *(const half8*)(Al + (wm * 64 + mt * 16 + l15) * 72 + ks * 32 + quad * 8);
#pragma unroll
            for (int nt = 0; nt < 4; ++nt)
                bfr[nt] = *(const half8*)(Bl + (wn * 64 + nt * 16 + l15) * 72 + ks * 32 + quad * 8);
#pragma unroll
            for (int mt = 0; mt < 4; ++mt)
#pragma unroll
                for (int nt = 0; nt < 4; ++nt)
                    acc[mt][nt] = __builtin_amdgcn_mfma_f32_16x16x32_f16(
                        af[mt], bfr[nt], acc[mt][nt], 0, 0, 0);
        }
        __syncthreads();
    }
#pragma unroll
    for (int mt = 0; mt < 4; ++mt) {
#pragma unroll
        for (int nt = 0; nt < 4; ++nt) {
            const int dl = wm * 64 + mt * 16 + quad * 4;       // C/D row = quad*4+reg
            const int jl = wn * 64 + nt * 16 + l15;            // C/D col = lane&15
            floatx4 v = acc[mt][nt];
#pragma unroll
            for (int r = 0; r < 4; ++r) v[r] = relu_keepnan(v[r]);
            if (MODE == 0) {
                ushort4v hv;
#pragma unroll
                for (int r = 0; r < 4; ++r) hv[r] = f2h(v[r]);
                *(ushort4v*)(o16 + (size_t)(j0 + jl) * 512 + m0 + dl) = hv;
                // stage f16 into lds tile [d][j] (stride 136) for the ut transpose
#pragma unroll
                for (int r = 0; r < 4; ++r) lds[(dl + r) * 136 + jl] = hv[r];
            } else {
                const int j = j0 + jl;
                const int bl = j >> 11, t = j & 2047;
#pragma unroll
                for (int r = 0; r < 4; ++r)
                    of32[((size_t)((b0 + bl) * 512 + m0 + dl + r)) * 2048 + t] = v[r];
            }
        }
    }
    if (MODE == 0) {
        __syncthreads();
        const int drow = tid >> 1, hh = tid & 1;
        const unsigned short* srcp = lds + drow * 136 + hh * 64;
        unsigned short* dstp = ut + (size_t)(m0 + drow) * J + j0 + hh * 64;
#pragma unroll
        for (int q = 0; q < 8; ++q)
            *(intx4*)(dstp + q * 8) = *(const intx4*)(srcp + q * 8);
    }
}

// ------- phase A GEMM + fused segment-prefix comb ------------------------------------
// P[h][n2][r] = sum_k WA[h][n2][k] * ut[h][r][k] stays in LDS; exclusive prefix over
// 16 segments runs in-block (block covers 8 batch elems x all 16 segs x all 64 n2).
// Eliminates the 32MB P global round-trip + the separate k_comb launch per layer.
__global__ __launch_bounds__(256, 4) void k_stateA_comb(
    const unsigned short* __restrict__ WA, const unsigned short* __restrict__ ut,
    const float2* __restrict__ wt, unsigned short* __restrict__ S0,
    int layer, int J, int Rtot) {
    __shared__ __align__(16) char smem[64 * 131 * 4];   // GEMM: Aw+Bw (27.6KB); epi: Ps
    unsigned short* Aw = (unsigned short*)smem;
    unsigned short* Bw = (unsigned short*)(smem + 64 * 72 * 2);
    float* Ps = (float*)smem;                            // [64][131] f32 (33.5KB)
    const int tid = threadIdx.x;
    const int h = blockIdx.y;
    const int r0 = blockIdx.x * 128;
    const int sub = tid & 7, row = tid >> 3;
    const unsigned short* Ag = WA + (size_t)h * 8192 + row * 128 + sub * 8;
    const unsigned short* Bg = ut + (size_t)h * J + (size_t)(r0 + row) * 128 + sub * 8;
    intx4 ra[2], rb[4];
    ra[0] = *(const intx4*)(Ag);
    ra[1] = *(const intx4*)(Ag + 32 * 128);
#pragma unroll
    for (int i = 0; i < 4; ++i) rb[i] = *(const intx4*)(Bg + i * 32 * 128);
    const int lane = tid & 63, w = tid >> 6;
    const int wm = w & 1, wn = w >> 1;
    const int l15 = lane & 15, quad = lane >> 4;
    floatx4 acc[2][4] = {};
    for (int kt = 0; kt < 2; ++kt) {
        *(intx4*)(Aw + row * 72 + sub * 8) = ra[0];
        *(intx4*)(Aw + (row + 32) * 72 + sub * 8) = ra[1];
#pragma unroll
        for (int i = 0; i < 4; ++i)
            *(intx4*)(Bw + (row + 32 * i) * 72 + sub * 8) = rb[i];
        __syncthreads();
        if (kt == 0) {
            ra[0] = *(const intx4*)(Ag + 64);
            ra[1] = *(const intx4*)(Ag + 32 * 128 + 64);
#pragma unroll
            for (int i = 0; i < 4; ++i) rb[i] = *(const intx4*)(Bg + i * 32 * 128 + 64);
        }
#pragma unroll
        for (int ks = 0; ks < 2; ++ks) {
            half8 af[2], bfr[4];
#pragma unroll
            for (int mt = 0; mt < 2; ++mt)
                af[mt] = *(const half8*)(Aw + (wm * 32 + mt * 16 + l15) * 72 + ks * 32 + quad * 8);
#pragma unroll
            for (int nt = 0; nt < 4; ++nt)
                bfr[nt] = *(const half8*)(Bw + (wn * 64 + nt * 16 + l15) * 72 + ks * 32 + quad * 8);
#pragma unroll
            for (int mt = 0; mt < 2; ++mt)
#pragma unroll
                for (int nt = 0; nt < 4; ++nt)
                    acc[mt][nt] = __builtin_amdgcn_mfma_f32_16x16x32_f16(
                        af[mt], bfr[nt], acc[mt][nt], 0, 0, 0);
        }
        __syncthreads();
    }
    // acc -> Ps (Aw/Bw dead after the loop's trailing barrier)
#pragma unroll
    for (int mt = 0; mt < 2; ++mt)
#pragma unroll
        for (int nt = 0; nt < 4; ++nt)
#pragma unroll
            for (int r = 0; r < 4; ++r)
                Ps[(wm * 32 + mt * 16 + quad * 4 + r) * 131 +
                   wn * 64 + nt * 16 + l15] = acc[mt][nt][r];
    __syncthreads();
    // comb: n = tid&31, b-local = tid>>5; serial over 16 segments; coalesced S0 stores
    const int n = tid & 31, bl = tid >> 5;
    const float2 wv = wt[((size_t)layer * 32 + n) * 512 + h];
    unsigned int* S0w = (unsigned int*)(S0 + ((size_t)h * Rtot + r0 + bl * 16) * 64) + n;
    float ar = 0.f, ai = 0.f;
#pragma unroll
    for (int g = 0; g < 16; ++g) {
        S0w[g * 32] = (unsigned int)f2h(ar) | ((unsigned int)f2h(ai) << 16);
        float pr = Ps[(2 * n) * 131 + bl * 16 + g];
        float pi = Ps[(2 * n + 1) * 131 + bl * 16 + g];
        float nr = fmaf(wv.x, ar, fmaf(-wv.y, ai, pr));
        float ni = fmaf(wv.x, ai, fmaf(wv.y, ar, pi));
        ar = nr; ai = ni;
    }
}

// ---------------- phase B GEMM + gelu: vt[h][r*128+t] = gelu(sum_k TT[t][k]*[ut|S0]) -
__global__ __launch_bounds__(256, 3) void k_applyB(
    const unsigned short* __restrict__ TT, const unsigned short* __restrict__ ut,
    const unsigned short* __restrict__ S0, unsigned short* __restrict__ vt,
    int J, int Rtot) {
    __shared__ __align__(16) unsigned short lds[2 * 128 * 72];
    unsigned short* Al = lds;
    unsigned short* Bl = lds + 128 * 72;
    const int tid = threadIdx.x;
    const int h = blockIdx.y;
    const int r0 = blockIdx.x * 128;
    const int sub = tid & 7, row = tid >> 3;
    const unsigned short* Ag = TT + (size_t)h * 24576 + row * 192 + sub * 8;
    const unsigned short* Bu = ut + (size_t)h * J + (size_t)(r0 + row) * 128 + sub * 8;
    const unsigned short* Bs = S0 + ((size_t)h * Rtot + r0 + row) * 64 + sub * 8;
    intx4 ra[4], rb[4];
#pragma unroll
    for (int i = 0; i < 4; ++i) {
        ra[i] = *(const intx4*)(Ag + i * 32 * 192);
        rb[i] = *(const intx4*)(Bu + i * 32 * 128);
    }
    const int lane = tid & 63, w = tid >> 6;
    const int wm = w & 1, wn = w >> 1;
    const int l15 = lane & 15, quad = lane >> 4;
    floatx4 acc[4][4] = {};
    for (int kt = 0; kt < 3; ++kt) {
#pragma unroll
        for (int i = 0; i < 4; ++i) {
            *(intx4*)(Al + (row + 32 * i) * 72 + sub * 8) = ra[i];
            *(intx4*)(Bl + (row + 32 * i) * 72 + sub * 8) = rb[i];
        }
        __syncthreads();
        if (kt == 0) {
#pragma unroll
            for (int i = 0; i < 4; ++i) {
                ra[i] = *(const intx4*)(Ag + i * 32 * 192 + 64);
                rb[i] = *(const intx4*)(Bu + i * 32 * 128 + 64);
            }
        } else if (kt == 1) {
#pragma unroll
            for (int i = 0; i < 4; ++i) {
                ra[i] = *(const intx4*)(Ag + i * 32 * 192 + 128);
                rb[i] = *(const intx4*)(Bs + i * 32 * 64);
            }
        }
#pragma unroll
        for (int ks = 0; ks < 2; ++ks) {
            half8 af[4], bfr[4];
#pragma unroll
            for (int mt = 0; mt < 4; ++mt)
                af[mt] = *(const half8*)(Al + (wm * 64 + mt * 16 + l15) * 72 + ks * 32 + quad * 8);
#pragma unroll
            for (int nt = 0; nt < 4; ++nt)
                bfr[nt] = *(const half8*)(Bl + (wn * 64 + nt * 16 + l15) * 72 + ks * 32 + quad * 8);
#pragma unroll
            for (int mt = 0; mt < 4; ++mt)
#pragma unroll
                for (int nt = 0; nt < 4; ++nt)
                    acc[mt][nt] = __builtin_amdgcn_mfma_f32_16x16x32_f16(
                        af[mt], bfr[nt], acc[mt][nt], 0, 0, 0);
        }
        __syncthreads();
    }
    // epilogue: gelu -> f16, LDS tile [r][t] (stride 136), then coalesced copy-out
#pragma unroll
    for (int mt = 0; mt < 4; ++mt)
#pragma unroll
        for (int nt = 0; nt < 4; ++nt) {
            const int tl = wm * 64 + mt * 16 + quad * 4;   // D row = t
            const int rl = wn * 64 + nt * 16 + l15;        // D col = r
            ushort4v pack;
#pragma unroll
            for (int r = 0; r < 4; ++r) {
                float y = acc[mt][nt][r];
                float ge = 0.5f * y * (1.f + erff(y * 0.70710678118654752f));
                pack[r] = f2h(ge);
            }
            *(ushort4v*)(lds + rl * 136 + tl) = pack;
        }
    __syncthreads();
    const int rl2 = tid >> 1, hh = tid & 1;
    const unsigned short* srcp = lds + rl2 * 136 + hh * 64;
    unsigned short* dstp = vt + (size_t)h * J + (size_t)(r0 + rl2) * 128 + hh * 64;
#pragma unroll
    for (int q = 0; q < 8; ++q)
        *(intx4*)(dstp + q * 8) = *(const intx4*)(srcp + q * 8);
}

// ------- fused W_out GEMM + GLU: g_out[j,d] = (a+b1)*sigmoid(g+b2), f16 out ----------
// Main loop = R6-proven (A/B LDS-staged, stride-72, XOR-swizzled B pack, 2 barriers/kt,
// prefetch between barrier and MFMAs; measured 60us). Epilogue = R7-proven f16 LDS
// transpose -> coalesced 16B stores (WRITE 74->35MB; f16 8B scattered stores cost +20us).
__global__ __launch_bounds__(256, 2) void k_gemm_glu(
    const unsigned short* __restrict__ A,   // W_out layer (1024,512) f16
    const unsigned short* __restrict__ Bt,  // vt (512, J) f16
    const float* __restrict__ bias,         // b_out layer (1024) f32
    unsigned short* __restrict__ g_out, int J) {  // (J,512) f16
    __shared__ __align__(16) unsigned short lds[3 * 128 * 72];
    unsigned short* A1l = lds;
    unsigned short* A2l = lds + 9216;
    unsigned short* Bl  = lds + 18432;
    const int tid = threadIdx.x;
    const int m0 = blockIdx.y * 128;
    const int j0 = blockIdx.x * 128;
    const int sub = tid & 7;
    const int row = tid >> 3;                        // 0..31
    const unsigned short* A1g = A + (size_t)(m0 + row) * 512 + sub * 8;
    const unsigned short* A2g = A1g + 512 * 512;
    // B staging map: channel pair (2*chp, 2*chp+1) chp 0..31, j-octets jo and jo+8
    const int chp = tid >> 3, jo = tid & 7;
    const unsigned short* Bg = Bt + (size_t)(2 * chp) * J + j0 + jo * 8;
    intx4 ra1[4], ra2[4], rb[4];
#pragma unroll
    for (int i = 0; i < 4; ++i) {
        ra1[i] = *(const intx4*)(A1g + (size_t)i * 32 * 512);
        ra2[i] = *(const intx4*)(A2g + (size_t)i * 32 * 512);
    }
    rb[0] = *(const intx4*)(Bg);
    rb[1] = *(const intx4*)(Bg + J);
    rb[2] = *(const intx4*)(Bg + 64);
    rb[3] = *(const intx4*)(Bg + J + 64);
    const int lane = tid & 63;
    const int w = tid >> 6;
    const int wm = w & 1, wn = w >> 1;               // 2x2 waves: m 2x64, n 2x64
    const int l15 = lane & 15, quad = lane >> 4;
    // swizzled column base for B writes: colblk' = (chp>>2) ^ ((j>>3)&7)
    const int colbase = (((chp >> 2) ^ jo) << 3) + (chp & 3) * 2;
    floatx4 ac1[4][4] = {}, ac2[4][4] = {};
    for (int kt = 0; kt < 8; ++kt) {
#pragma unroll
        for (int i = 0; i < 4; ++i) {
            *(intx4*)(A1l + (row + 32 * i) * 72 + sub * 8) = ra1[i];
            *(intx4*)(A2l + (row + 32 * i) * 72 + sub * 8) = ra2[i];
        }
        // B: pack channel pair into u32 words, write (j, chpair) with XOR-swizzle.
        // j-octets jo*8.. and (jo+8)*8..: (j>>3)&7 == jo for both -> same colbase.
        {
            unsigned int* B32 = (unsigned int*)Bl;
#pragma unroll
            for (int half = 0; half < 2; ++half) {
                const int jb = (jo + half * 8) * 8;
                intx4 e0 = rb[half * 2], e1 = rb[half * 2 + 1];
#pragma unroll
                for (int i = 0; i < 4; ++i) {
                    unsigned int ae = (unsigned int)e0[i], be = (unsigned int)e1[i];
                    unsigned int lo = (ae & 0xffffu) | (be << 16);        // j = jb+2i
                    unsigned int hi = (ae >> 16) | (be & 0xffff0000u);    // j = jb+2i+1
                    B32[((jb + 2 * i) * 72 + colbase) >> 1] = lo;
                    B32[((jb + 2 * i + 1) * 72 + colbase) >> 1] = hi;
                }
            }
        }
        __syncthreads();
        if (kt < 7) {
#pragma unroll
            for (int i = 0; i < 4; ++i) {
                ra1[i] = *(const intx4*)(A1g + (size_t)i * 32 * 512 + (kt + 1) * 64);
                ra2[i] = *(const intx4*)(A2g + (size_t)i * 32 * 512 + (kt + 1) * 64);
            }
            rb[0] = *(const intx4*)(Bg + (size_t)(kt + 1) * 64 * J);
            rb[1] = *(const intx4*)(Bg + (size_t)(kt + 1) * 64 * J + J);
            rb[2] = *(const intx4*)(Bg + (size_t)(kt + 1) * 64 * J + 64);
            rb[3] = *(const intx4*)(Bg + (size_t)(kt + 1) * 64 * J + J + 64);
        }
#pragma unroll
        for (int ks = 0; ks < 2; ++ks) {
            half8 af1[4], af2[4], bfr[4];
#pragma unroll
            for (int mt = 0; mt < 4; ++mt) {
                af1[mt] = *(const half8*)(A1l + (wm * 64 + mt * 16 + l15) * 72 + ks * 32 + quad * 8);
                af2[mt] = *(const half8*)(A2l + (wm * 64 + mt * 16 + l15) * 72 + ks * 32 + quad * 8);
            }
#pragma unroll
            for (int nt = 0; nt < 4; ++nt) {
                const int rr = wn * 64 + nt * 16 + l15;
                const int cb = (ks * 4 + quad) ^ ((rr >> 3) & 7);
                bfr[nt] = *(const half8*)(Bl + rr * 72 + cb * 8);
            }
#pragma unroll
            for (int mt = 0; mt < 4; ++mt)
#pragma unroll
                for (int nt = 0; nt < 4; ++nt) {
                    ac1[mt][nt] = __builtin_amdgcn_mfma_f32_16x16x32_f16(
                        af1[mt], bfr[nt], ac1[mt][nt], 0, 0, 0);
                    ac2[mt][nt] = __builtin_amdgcn_mfma_f32_16x16x32_f16(
                        af2[mt], bfr[nt], ac2[mt][nt], 0, 0, 0);
                }
        }
        __syncthreads();
    }
    // epilogue: GLU -> f16 tile [j][d] (stride 136, reuses A1l+A2l region: 17408 < 18432),
    // then coalesced 16B copy-out. Loop's trailing barrier fences the LDS reuse.
#pragma unroll
    for (int mt = 0; mt < 4; ++mt) {
#pragma unroll
        for (int nt = 0; nt < 4; ++nt) {
            const int dl = wm * 64 + mt * 16 + quad * 4;
            const int jl = wn * 64 + nt * 16 + l15;
            ushort4v p;
#pragma unroll
            for (int r = 0; r < 4; ++r) {
                float a = ac1[mt][nt][r] + bias[m0 + dl + r];
                float gg = ac2[mt][nt][r] + bias[512 + m0 + dl + r];
                p[r] = f2h(a / (1.f + expf(-gg)));
            }
            *(ushort4v*)(lds + jl * 136 + dl) = p;
        }
    }
    __syncthreads();
    const int r2 = tid >> 1, hh = tid & 1;
    const unsigned short* srcp = lds + r2 * 136 + hh * 64;
    unsigned short* dstp = g_out + (size_t)(j0 + r2) * 512 + m0 + hh * 64;
#pragma unroll
    for (int q = 0; q < 8; ++q)
        *(intx4*)(dstp + q * 8) = *(const intx4*)(srcp + q * 8);
}

// ------- residual + LayerNorm, fused transposed-f16 output (g, hf both f16) ---------
// 32 j-rows per block, values held in registers (no re-read).
// mode 1: emit hf + ut (512,J) via swizzled LDS transpose; mode 2: emit hb (J,512).
__global__ __launch_bounds__(256, 4) void k_res_ln_t(
    const unsigned short* __restrict__ g, unsigned short* __restrict__ hf,
    unsigned short* __restrict__ ut, unsigned short* __restrict__ hb,
    const float* __restrict__ lng, const float* __restrict__ lnb,
    int layer, int J, int mode) {
    __shared__ unsigned short tile[64 * 40];
    const int tid = threadIdx.x;
    const int r = tid >> 3, sub = tid & 7;          // 32 rows x 8 lanes/row
    const int j0 = blockIdx.x * 32;
    const size_t j = (size_t)j0 + r;
    const unsigned short* gj = g + j * 512;
    unsigned short* hj = hf + j * 512;
    floatx4 v[16];
    float s1 = 0.f, s2 = 0.f;
#pragma unroll
    for (int k = 0; k < 16; ++k) {
        ushort4v gv = *(const ushort4v*)(gj + sub * 4 + k * 32);
        ushort4v hv = *(const ushort4v*)(hj + sub * 4 + k * 32);
        floatx4 vv;
#pragma unroll
        for (int i = 0; i < 4; ++i) vv[i] = h2f(gv[i]) + h2f(hv[i]);  // residual
        v[k] = vv;
        s1 += vv[0] + vv[1] + vv[2] + vv[3];
        s2 += vv[0] * vv[0] + vv[1] * vv[1] + vv[2] * vv[2] + vv[3] * vv[3];
    }
#pragma unroll
    for (int m = 4; m >= 1; m >>= 1) { s1 += __shfl_xor(s1, m, 64); s2 += __shfl_xor(s2, m, 64); }
    const float mu = s1 * (1.f / 512.f);
    const float var = s2 * (1.f / 512.f) - mu * mu;
    const float isd = 1.f / sqrtf(var + 1e-5f);
#pragma unroll
    for (int t = 0; t < 8; ++t) {
        if (mode == 1 && t) __syncthreads();        // protect tile reuse
#pragma unroll
        for (int kk = 0; kk < 2; ++kk) {
            const int k = t * 2 + kk;
            const int cho = sub * 4 + k * 32;       // global ch of elem 0
            floatx4 gw = *(const floatx4*)(lng + layer * 512 + cho);
            floatx4 bw = *(const floatx4*)(lnb + layer * 512 + cho);
            ushort4v p;
#pragma unroll
            for (int i = 0; i < 4; ++i)
                p[i] = f2h((v[k][i] - mu) * isd * gw[i] + bw[i]);
            if (mode == 1) {
                *(ushort4v*)(hj + cho) = p;
                const int chl = kk * 32 + sub * 4;  // ch-local within 64-ch tile
#pragma unroll
                for (int i = 0; i < 4; ++i)
                    tile[(chl + i) * 40 + (r ^ ((((chl + i) >> 2) & 3) << 3))] = p[i];
            } else {
                *(ushort4v*)(hb + j * 512 + cho) = p;
            }
        }
        if (mode == 1) {
            __syncthreads();
            const int chrow = tid >> 2, part = tid & 3;   // 64 ch rows x 4 parts
            const int pb = part ^ ((chrow >> 2) & 3);     // un-swizzle j-block
            *(intx4*)(ut + (size_t)(t * 64 + chrow) * J + j0 + part * 8) =
                *(const intx4*)(tile + chrow * 40 + pb * 8);
        }
    }
}

extern "C" void kernel_launch(void* const* d_in, const int* in_sizes, int n_in,
                              void* d_out, int out_size, void* d_ws, size_t ws_size,
                              hipStream_t stream) {
    (void)in_sizes; (void)n_in; (void)out_size;
    const float* x      = (const float*)d_in[0];
    const float* W_enc  = (const float*)d_in[1];
    const float* W_dec  = (const float*)d_in[2];
    const float* log_dt = (const float*)d_in[3];
    const float* log_Ar = (const float*)d_in[4];
    const float* A_im   = (const float*)d_in[5];
    const float* C_re   = (const float*)d_in[6];
    const float* C_im   = (const float*)d_in[7];
    const float* Dp     = (const float*)d_in[8];
    const float* W_out  = (const float*)d_in[9];
    const float* b_out  = (const float*)d_in[10];
    const float* ln_g   = (const float*)d_in[11];
    const float* ln_b   = (const float*)d_in[12];

    // fixed ~42MiB (lwc/wt/weights/WA/TT) + per-batch-elem 9MiB (ut 2 + scan 3 + hf 2 + vt 2)
    int C = 16;
    while (C > 8 && (size_t)C * (9ull << 20) + (42ull << 20) > ws_size) C >>= 1;
    const size_t J = (size_t)C * 2048;
    const int Rtot = C * 16;

    char* ws = (char*)d_ws;
    size_t off = 0;
    auto alloc = [&](size_t bytes) { void* p = ws + off; off += (bytes + 255) & ~(size_t)255; return p; };
    float4*         lwc   = (float4*)alloc(4ull * 512 * 32 * 16);
    float2*         wt    = (float2*)alloc(4ull * 512 * 32 * 8);
    unsigned short* wencb = (unsigned short*)alloc(512 * 512 * 2);
    unsigned short* wdecb = (unsigned short*)alloc(512 * 512 * 2);
    unsigned short* woutb = (unsigned short*)alloc(4ull * 1024 * 512 * 2);
    unsigned short* WAb   = (unsigned short*)alloc(512ull * 64 * 128 * 2);   // per-layer
    unsigned short* TTb   = (unsigned short*)alloc(512ull * 128 * 192 * 2);  // per-layer
    unsigned short* ut    = (unsigned short*)alloc(512ull * J * 2);          // (512,J) f16
    char*           scan  = (char*)alloc((size_t)C * (3ull << 20));  // g16 + S0; xq alias
    unsigned short* hf    = (unsigned short*)alloc(J * 512 * 2);     // h (J,512) f16
    unsigned short* vt    = (unsigned short*)alloc(J * 512 * 2);     // gelu out (512,J); hb alias
    unsigned short* g16   = (unsigned short*)scan;   // GLU out (J,512) f16, 2C MiB
    unsigned short* xq    = (unsigned short*)scan;   // dead after encoder GEMM
    unsigned short* hb    = vt;                      // vt dead after layer-3 GLU GEMM
    unsigned short* S0u   = (unsigned short*)(scan + (size_t)C * (2ull << 20));

    k_precompute<<<256, 256, 0, stream>>>(log_dt, log_Ar, A_im, C_re, C_im, lwc, wt);
    k_cvt<<<1024, 256, 0, stream>>>(W_enc, wencb, 512 * 512);
    k_cvt<<<1024, 256, 0, stream>>>(W_dec, wdecb, 512 * 512);
    k_cvt<<<8192, 256, 0, stream>>>(W_out, woutb, 4 * 1024 * 512);
    for (int b0 = 0; b0 < 16; b0 += C) {
        k_quant_transpose<<<dim3(32, 8, C), 256, 0, stream>>>(x, xq, b0);
        k_gemm<0><<<dim3(C * 16, 4), 256, 0, stream>>>(wencb, xq, nullptr, hf, ut, (int)J, 0);
        for (int i = 0; i < 4; ++i) {
            k_build_wa<<<512, 64, 0, stream>>>(lwc, WAb, i);
            k_build_T<<<512, 256, 0, stream>>>(lwc, Dp, TTb, i);
            k_stateA_comb<<<dim3(Rtot / 128, 512), 256, 0, stream>>>(
                WAb, ut, wt, S0u, i, (int)J, Rtot);
            k_applyB<<<dim3(Rtot / 128, 512), 256, 0, stream>>>(TTb, ut, S0u, vt, (int)J, Rtot);
            k_gemm_glu<<<dim3(C * 16, 4), 256, 0, stream>>>(
                woutb + (size_t)i * 1024 * 512, vt, b_out + (size_t)i * 1024, g16, (int)J);
            k_res_ln_t<<<(int)(J / 32), 256, 0, stream>>>(
                g16, hf, ut, hb, ln_g, ln_b, i, (int)J, (i == 3) ? 2 : 1);
        }
        k_gemm<2><<<dim3(C * 16, 4), 256, 0, stream>>>(wdecb, hb, (float*)d_out, nullptr, nullptr, (int)J, b0);
    }
}